// Round 5
// baseline (1424.990 us; speedup 1.0000x reference)
//
#include <hip/hip_runtime.h>

typedef unsigned short bf16_t;  // raw bf16 bits
typedef __attribute__((ext_vector_type(8))) short bf16x8;
typedef __attribute__((ext_vector_type(4))) float f32x4;

static constexpr int NU = 100000;   // users
static constexpr int NG = 20000;    // games
static constexpr int HD = 256;      // hidden
static constexpr int EE = 1000000;  // edges per direction
static constexpr int SS = 500000;   // score pairs
static constexpr int NBKT_G = (NG + 127) / 128;  // 157 coarse buckets (games)
static constexpr int NBKT_U = (NU + 127) / 128;  // 782 coarse buckets (users)

// ---------------- bf16 helpers ----------------
__device__ __forceinline__ float b2f(bf16_t u) {
    union { unsigned int i; float f; } x; x.i = ((unsigned int)u) << 16; return x.f;
}
__device__ __forceinline__ bf16_t f2b(float f) {
    union { float f; unsigned int i; } x; x.f = f;
    unsigned int r = x.i + 0x7FFF + ((x.i >> 16) & 1);  // RNE
    return (bf16_t)(r >> 16);
}

// accumulate 8 bf16 (packed in uint4) * w into acc[8]
__device__ __forceinline__ void accum8(float* acc, uint4 r, float w) {
    unsigned int u[4] = {r.x, r.y, r.z, r.w};
#pragma unroll
    for (int i = 0; i < 4; i++) {
        float lo = __uint_as_float(u[i] << 16);
        float hi = __uint_as_float(u[i] & 0xFFFF0000u);
        acc[2 * i]     = fmaf(w, lo, acc[2 * i]);
        acc[2 * i + 1] = fmaf(w, hi, acc[2 * i + 1]);
    }
}

// ---------------- preprocessing ----------------
// xg = bf16(concat(x_game, emb_game)); xu = bf16(x_user); also zero coarse counters
__global__ void prep_feats(const float* __restrict__ xgame, const float* __restrict__ emb,
                           const float* __restrict__ xuser,
                           bf16_t* __restrict__ xg, bf16_t* __restrict__ xu,
                           int* __restrict__ cg, int* __restrict__ cu) {
    int id = blockIdx.x * 256 + threadIdx.x;
    if (id < NBKT_G * 8) cg[id] = 0;
    if (id < NBKT_U * 8) cu[id] = 0;
    const int ng4 = NG * 32;  // NG*128/4
    if (id < ng4) {
        int r = id >> 5, c = (id & 31) * 4;
        float4 v = (c < 64) ? *(const float4*)&xgame[(size_t)r * 64 + c]
                            : *(const float4*)&emb[(size_t)r * 64 + (c - 64)];
        ((ushort4*)xg)[id] = make_ushort4(f2b(v.x), f2b(v.y), f2b(v.z), f2b(v.w));
    } else {
        int j = id - ng4;
        if (j >= NU * 32) return;
        float4 v = ((const float4*)xuser)[j];
        ((ushort4*)xu)[j] = make_ushort4(f2b(v.x), f2b(v.y), f2b(v.z), f2b(v.w));
    }
}

// all 12 weights: K x 256 fp32 row-major -> 256 x K bf16 (transpose+convert)
struct WtArgs {
    const float* src[12];
    bf16_t* dst[12];
    int K[12];
    int off[13];
};
__global__ void wt_all(WtArgs a, int total) {
    int id = blockIdx.x * 256 + threadIdx.x;
    if (id >= total) return;
    int s = 0;
    while (id >= a.off[s + 1]) ++s;
    int local = id - a.off[s];
    int K = a.K[s];
    int k = local >> 8, n = local & 255;
    a.dst[s][(size_t)n * K + k] = f2b(a.src[s][local]);
}

// ---------------- CSR build: two-level radix partition ----------------
// Coarse bucket = dst>>7. 8 sub-slots per bucket keyed by (block&7) so each
// sub-region receives consecutive writes from one XCD (blockIdx%8 round-robin).
static constexpr int CHUNK = (EE + 255) / 256;  // edges per block (256 blocks/dir)

__global__ void chisto(const int* __restrict__ dug, const int* __restrict__ dgu,
                       int* __restrict__ cg, int* __restrict__ cu) {
    int b = blockIdx.x;
    int dir = b >> 8, lb = b & 255, hint = lb & 7;
    const int* dst = dir ? dgu : dug;
    int* cnt = dir ? cu : cg;
    int beg = lb * CHUNK, fin = min(EE, beg + CHUNK);
    for (int i = beg + threadIdx.x; i < fin; i += 256)
        atomicAdd(&cnt[(((unsigned)dst[i]) >> 7) * 8 + hint], 1);
}

// exclusive scan of coarse counters (block0: games, block1: users); zero cursors
__global__ void scan_coarse(const int* __restrict__ cg, int* __restrict__ bg,
                            const int* __restrict__ cu, int* __restrict__ bu,
                            int* __restrict__ curg, int* __restrict__ curu,
                            int* __restrict__ rpg, int* __restrict__ rpu) {
    __shared__ int sums[256];
    const int n = (blockIdx.x == 0) ? NBKT_G * 8 : NBKT_U * 8;
    const int* src = (blockIdx.x == 0) ? cg : cu;
    int* dst = (blockIdx.x == 0) ? bg : bu;
    int* cur = (blockIdx.x == 0) ? curg : curu;
    int t = threadIdx.x;
    int c = (n + 255) / 256;
    for (int i = t; i < n; i += 256) cur[i] = 0;
    int s = 0;
    for (int i = 0; i < c; i++) { int idx = t * c + i; s += (idx < n) ? src[idx] : 0; }
    sums[t] = s;
    __syncthreads();
    for (int off = 1; off < 256; off <<= 1) {
        int y = (t >= off) ? sums[t - off] : 0;
        __syncthreads();
        sums[t] += y;
        __syncthreads();
    }
    int run = sums[t] - s;
    for (int i = 0; i < c; i++) {
        int idx = t * c + i;
        if (idx < n) { int v = src[idx]; dst[idx] = run; run += v; }
    }
    if (blockIdx.x == 0 && t == 0) rpg[NG] = EE;
    if (blockIdx.x == 1 && t == 0) rpu[NU] = EE;
}

// coarse scatter into bucket sub-regions; entry packs (src | dstLocal<<17, w)
__global__ void passA(const int* __restrict__ sug, const int* __restrict__ dug,
                      const float* __restrict__ wug,
                      const int* __restrict__ sgu, const int* __restrict__ dgu,
                      const float* __restrict__ wgu,
                      const int* __restrict__ bg, const int* __restrict__ bu,
                      int* __restrict__ curg, int* __restrict__ curu,
                      int2* __restrict__ tmpG, int2* __restrict__ tmpU) {
    int b = blockIdx.x;
    int dir = b >> 8, lb = b & 255, hint = lb & 7;
    const int* src = dir ? sgu : sug;
    const int* dst = dir ? dgu : dug;
    const float* w = dir ? wgu : wug;
    const int* base = dir ? bu : bg;
    int* cur = dir ? curu : curg;
    int2* tmp = dir ? tmpU : tmpG;
    int beg = lb * CHUNK, fin = min(EE, beg + CHUNK);
    for (int i = beg + threadIdx.x; i < fin; i += 256) {
        unsigned d = (unsigned)dst[i];
        int slot = (d >> 7) * 8 + hint;
        int pos = base[slot] + atomicAdd(&cur[slot], 1);
        tmp[pos] = make_int2(src[i] | ((d & 127u) << 17), __float_as_int(w[i]));
    }
}

// fine scatter within each bucket (one WG per bucket); also emits rowptr
__global__ __launch_bounds__(256) void passB(
    const int2* __restrict__ tmpG, const int2* __restrict__ tmpU,
    const int* __restrict__ bg, const int* __restrict__ bu,
    int* __restrict__ rpg, int* __restrict__ rpu,
    int2* __restrict__ eug, int2* __restrict__ egu) {
    int b = blockIdx.x;
    const int2* tmp; const int* base; int* rowptr; int2* eout; int bucket, nbkt, ntot;
    if (b < NBKT_G) { tmp = tmpG; base = bg; rowptr = rpg; eout = eug; bucket = b; nbkt = NBKT_G; ntot = NG; }
    else            { tmp = tmpU; base = bu; rowptr = rpu; eout = egu; bucket = b - NBKT_G; nbkt = NBKT_U; ntot = NU; }
    int start = base[bucket * 8];
    int end = (bucket == nbkt - 1) ? EE : base[(bucket + 1) * 8];
    int row0 = bucket * 128;
    int nrows = min(128, ntot - row0);
    __shared__ int hist[128], excl[128], cur[128];
    int t = threadIdx.x;
    if (t < 128) { hist[t] = 0; cur[t] = 0; }
    __syncthreads();
    for (int i = start + t; i < end; i += 256)
        atomicAdd(&hist[((unsigned)tmp[i].x) >> 17], 1);
    __syncthreads();
    if (t == 0) {
        int run = 0;
        for (int l = 0; l < 128; l++) { excl[l] = run; run += hist[l]; }
    }
    __syncthreads();
    if (t < nrows) rowptr[row0 + t] = start + excl[t];
    for (int i = start + t; i < end; i += 256) {
        int2 e = tmp[i];
        int dl = ((unsigned)e.x) >> 17;
        int pos = start + excl[dl] + atomicAdd(&cur[dl], 1);
        eout[pos] = make_int2(e.x & 0x1FFFF, e.y);
    }
}

// ---------------- segment sum: wave split into D/8-lane subgroups ----------------
// 16 B loads, 4x unroll => 8 independent edge-row loads in flight per wave.
template <int D>  // 128 or 256
__global__ __launch_bounds__(256) void seg_sum16(
    const bf16_t* __restrict__ feat, const int* __restrict__ rowptr,
    const int2* __restrict__ edges, bf16_t* __restrict__ out, int n_rows) {
    constexpr int LPE = D / 8;    // lanes per edge-row (16 B each)
    constexpr int EP = 64 / LPE;  // edges per batch
    constexpr int UN = 4;         // batches in flight
    int wid = (blockIdx.x * 256 + threadIdx.x) >> 6;
    int lane = threadIdx.x & 63;
    if (wid >= n_rows) return;
    int beg = rowptr[wid], end = rowptr[wid + 1];
    const int h = lane / LPE;
    const int cl = lane % LPE;
    const uint4* fb = (const uint4*)feat;
    float acc[8] = {};
    for (int eb = beg; eb < end; eb += UN * EP) {
        int2 ed[UN]; bool v[UN]; uint4 r[UN];
#pragma unroll
        for (int u = 0; u < UN; u++) {
            int e = eb + u * EP + h;
            v[u] = e < end;
            ed[u] = edges[v[u] ? e : beg];
        }
#pragma unroll
        for (int u = 0; u < UN; u++)
            r[u] = fb[(size_t)ed[u].x * (D / 8) + cl];
#pragma unroll
        for (int u = 0; u < UN; u++)
            accum8(acc, r[u], v[u] ? __int_as_float(ed[u].y) : 0.f);
    }
#pragma unroll
    for (int k = 0; k < 8; ++k) {
        acc[k] += __shfl_down(acc[k], 32, 64);
        if (LPE == 16) acc[k] += __shfl_down(acc[k], 16, 64);
    }
    if (lane < LPE) {
        uint4 o;
        o.x = (unsigned)f2b(acc[0]) | ((unsigned)f2b(acc[1]) << 16);
        o.y = (unsigned)f2b(acc[2]) | ((unsigned)f2b(acc[3]) << 16);
        o.z = (unsigned)f2b(acc[4]) | ((unsigned)f2b(acc[5]) << 16);
        o.w = (unsigned)f2b(acc[6]) | ((unsigned)f2b(acc[7]) << 16);
        ((uint4*)(out + (size_t)wid * D))[lane] = o;
    }
}

// ---------------- MFMA GEMM: C(bf16,[M,256]) = A1@W1 (+A2@W2) (+bias) (+C) (relu?) ----
template <bool TWOPASS>
__global__ __launch_bounds__(256) void gemm_mfma(
    const bf16_t* __restrict__ A1, const bf16_t* __restrict__ W1t,
    const bf16_t* __restrict__ A2, const bf16_t* __restrict__ W2t,
    const float* __restrict__ bias, bf16_t* __restrict__ C,
    int M, int K, int addc, int relu) {
    constexpr int LS = 40;
    __shared__ bf16_t As[128 * LS];
    __shared__ bf16_t Bs[128 * LS];
    const int t = threadIdx.x;
    const int lane = t & 63, wave = t >> 6;
    const int wm = (wave >> 1) * 64, wn = (wave & 1) * 64;
    const int rowBase = blockIdx.x * 128;
    const int colBase = blockIdx.y * 128;
    const int lm = lane & 15;
    const int quad = lane >> 4;
    f32x4 acc[4][4] = {};

    const int npass = TWOPASS ? 2 : 1;
    for (int pass = 0; pass < npass; ++pass) {
        const bf16_t* A = pass ? A2 : A1;
        const bf16_t* Wt = pass ? W2t : W1t;
        for (int k0 = 0; k0 < K; k0 += 32) {
#pragma unroll
            for (int i = 0; i < 2; ++i) {
                int li = t + i * 256;
                int r = li >> 2, c = (li & 3) * 8;
                int gm = rowBase + r;
                bf16x8 v = {};
                if (gm < M) v = *(const bf16x8*)&A[(size_t)gm * K + k0 + c];
                *(bf16x8*)&As[r * LS + c] = v;
            }
#pragma unroll
            for (int i = 0; i < 2; ++i) {
                int li = t + i * 256;
                int r = li >> 2, c = (li & 3) * 8;
                bf16x8 v = *(const bf16x8*)&Wt[(size_t)(colBase + r) * K + k0 + c];
                *(bf16x8*)&Bs[r * LS + c] = v;
            }
            __syncthreads();
            bf16x8 af[4], bfr[4];
#pragma unroll
            for (int i = 0; i < 4; ++i)
                af[i] = *(const bf16x8*)&As[(wm + i * 16 + lm) * LS + quad * 8];
#pragma unroll
            for (int j = 0; j < 4; ++j)
                bfr[j] = *(const bf16x8*)&Bs[(wn + j * 16 + lm) * LS + quad * 8];
#pragma unroll
            for (int i = 0; i < 4; ++i)
#pragma unroll
                for (int j = 0; j < 4; ++j)
                    acc[i][j] = __builtin_amdgcn_mfma_f32_16x16x32_bf16(af[i], bfr[j], acc[i][j], 0, 0, 0);
            __syncthreads();
        }
    }

#pragma unroll
    for (int j = 0; j < 4; ++j) {
        int col = colBase + wn + j * 16 + lm;
        float bj = bias ? bias[col] : 0.f;
#pragma unroll
        for (int i = 0; i < 4; ++i) {
            int row0 = rowBase + wm + i * 16 + quad * 4;
#pragma unroll
            for (int r = 0; r < 4; ++r) {
                int row = row0 + r;
                if (row >= M) continue;
                float v = acc[i][j][r] + bj;
                bf16_t* cp = &C[(size_t)row * HD + col];
                if (addc) v += b2f(*cp);
                if (relu) v = fmaxf(v, 0.f);
                *cp = f2b(v);
            }
        }
    }
}

// ---------------- decoder: 2 pairs per wave, 16 B loads ----------------
__global__ __launch_bounds__(256) void decode2(
    const bf16_t* __restrict__ u3, const bf16_t* __restrict__ g3,
    const int* __restrict__ row, const int* __restrict__ col,
    float* __restrict__ out, int S) {
    int wid = (blockIdx.x * 256 + threadIdx.x) >> 6;
    int lane = threadIdx.x & 63;
    int p = wid * 2 + (lane >> 5);
    int cl = lane & 31;
    if (p >= S) p = S - 1;  // tail lanes recompute last pair (benign dup store)
    int r = row[p], c = col[p];
    uint4 a = ((const uint4*)(u3 + (size_t)r * 256))[cl];
    uint4 b = ((const uint4*)(g3 + (size_t)c * 256))[cl];
    float s = 0.f;
    unsigned ua[4] = {a.x, a.y, a.z, a.w}, ub[4] = {b.x, b.y, b.z, b.w};
#pragma unroll
    for (int i = 0; i < 4; i++) {
        float alo = __uint_as_float(ua[i] << 16), ahi = __uint_as_float(ua[i] & 0xFFFF0000u);
        float blo = __uint_as_float(ub[i] << 16), bhi = __uint_as_float(ub[i] & 0xFFFF0000u);
        s = fmaf(alo, blo, s);
        s = fmaf(ahi, bhi, s);
    }
#pragma unroll
    for (int d = 16; d > 0; d >>= 1) s += __shfl_down(s, d, 64);
    if (cl == 0) out[p] = s;
}

extern "C" void kernel_launch(void* const* d_in, const int* in_sizes, int n_in,
                              void* d_out, int out_size, void* d_ws, size_t ws_size,
                              hipStream_t stream) {
    const float* x_user  = (const float*)d_in[0];
    const float* x_game  = (const float*)d_in[1];
    const float* emb_game= (const float*)d_in[2];
    const float* ew_ug   = (const float*)d_in[3];
    const float* ew_gu   = (const float*)d_in[4];
    const int* src_ug    = (const int*)d_in[5];
    const int* dst_ug    = (const int*)d_in[6];
    const int* src_gu    = (const int*)d_in[7];
    const int* dst_gu    = (const int*)d_in[8];
    const int* score_row = (const int*)d_in[9];
    const int* score_col = (const int*)d_in[10];
    const float* Wr_ug[3] = {(const float*)d_in[11], (const float*)d_in[17], (const float*)d_in[23]};
    const float* b_ug[3]  = {(const float*)d_in[12], (const float*)d_in[18], (const float*)d_in[24]};
    const float* Wo_g[3]  = {(const float*)d_in[13], (const float*)d_in[19], (const float*)d_in[25]};
    const float* Wr_gu[3] = {(const float*)d_in[14], (const float*)d_in[20], (const float*)d_in[26]};
    const float* b_gu[3]  = {(const float*)d_in[15], (const float*)d_in[21], (const float*)d_in[27]};
    const float* Wo_u[3]  = {(const float*)d_in[16], (const float*)d_in[22], (const float*)d_in[28]};
    float* out = (float*)d_out;
    (void)in_sizes; (void)n_in; (void)out_size;

    constexpr size_t WS_NEEDED = 183500000;
    if (ws_size < WS_NEEDED) return;  // clean fail, no OOB fault

    char* ws = (char*)d_ws;
    size_t off = 0;
    auto alloc = [&](size_t bytes) -> void* {
        void* p = ws + off;
        off += (bytes + 255) & ~(size_t)255;
        return p;
    };
    bf16_t* xg   = (bf16_t*)alloc((size_t)NG * 128 * 2);
    bf16_t* xu   = (bf16_t*)alloc((size_t)NU * 128 * 2);
    bf16_t* uA   = (bf16_t*)alloc((size_t)NU * HD * 2);
    bf16_t* uB   = (bf16_t*)alloc((size_t)NU * HD * 2);
    bf16_t* gA   = (bf16_t*)alloc((size_t)NG * HD * 2);
    bf16_t* gB   = (bf16_t*)alloc((size_t)NG * HD * 2);
    bf16_t* buf  = (bf16_t*)alloc((size_t)NG * HD * 2);
    int2*   e_ug = (int2*)  alloc((size_t)EE * 8);
    int2*   e_gu = (int2*)  alloc((size_t)EE * 8);
    bf16_t* WrugT[3], *WogT[3], *WrguT[3], *WouT[3];
    const int Ks[3] = {128, 256, 256};
    for (int l = 0; l < 3; ++l) {
        WrugT[l] = (bf16_t*)alloc((size_t)Ks[l] * HD * 2);
        WogT[l]  = (bf16_t*)alloc((size_t)Ks[l] * HD * 2);
        WrguT[l] = (bf16_t*)alloc((size_t)Ks[l] * HD * 2);
        WouT[l]  = (bf16_t*)alloc((size_t)Ks[l] * HD * 2);
    }
    int* rowptr_g = (int*)alloc((NG + 1) * 4);
    int* rowptr_u = (int*)alloc((NU + 1) * 4);
    int* cnt_g    = (int*)alloc(NBKT_G * 8 * 4);
    int* cnt_u    = (int*)alloc(NBKT_U * 8 * 4);
    int* base_g   = (int*)alloc(NBKT_G * 8 * 4);
    int* base_u   = (int*)alloc(NBKT_U * 8 * 4);
    int* cur_g    = (int*)alloc(NBKT_G * 8 * 4);
    int* cur_u    = (int*)alloc(NBKT_U * 8 * 4);
    // tmp partition buffers alias uB (first used in layer 2, after passB completes)
    int2* tmp_g = (int2*)uB;
    int2* tmp_u = tmp_g + EE;

    // ---- preprocessing ----
    {
        int n4 = NG * 32 + NU * 32;
        prep_feats<<<(n4 + 255) / 256, 256, 0, stream>>>(x_game, emb_game, x_user, xg, xu,
                                                         cnt_g, cnt_u);
        WtArgs wa;
        const float* srcs[12] = {Wr_ug[0], Wo_g[0], Wr_gu[0], Wo_u[0],
                                 Wr_ug[1], Wo_g[1], Wr_gu[1], Wo_u[1],
                                 Wr_ug[2], Wo_g[2], Wr_gu[2], Wo_u[2]};
        bf16_t* dsts[12] = {WrugT[0], WogT[0], WrguT[0], WouT[0],
                            WrugT[1], WogT[1], WrguT[1], WouT[1],
                            WrugT[2], WogT[2], WrguT[2], WouT[2]};
        int total = 0;
        for (int i = 0; i < 12; ++i) {
            wa.src[i] = srcs[i]; wa.dst[i] = dsts[i];
            wa.K[i] = Ks[i / 4]; wa.off[i] = total;
            total += Ks[i / 4] * HD;
        }
        wa.off[12] = total;
        wt_all<<<(total + 255) / 256, 256, 0, stream>>>(wa, total);
    }
    // ---- CSR build: coarse histo -> scan -> coarse scatter -> fine scatter ----
    chisto<<<512, 256, 0, stream>>>(dst_ug, dst_gu, cnt_g, cnt_u);
    scan_coarse<<<2, 256, 0, stream>>>(cnt_g, base_g, cnt_u, base_u, cur_g, cur_u,
                                       rowptr_g, rowptr_u);
    passA<<<512, 256, 0, stream>>>(src_ug, dst_ug, ew_ug, src_gu, dst_gu, ew_gu,
                                   base_g, base_u, cur_g, cur_u, tmp_g, tmp_u);
    passB<<<NBKT_G + NBKT_U, 256, 0, stream>>>(tmp_g, tmp_u, base_g, base_u,
                                               rowptr_g, rowptr_u, e_ug, e_gu);

    const dim3 GG((NG + 127) / 128, 2), GU((NU + 127) / 128, 2);
    const int SEG_G = (NG + 3) / 4, SEG_U = (NU + 3) / 4;

    // ---- Layer 1 (K=128) ----
    seg_sum16<128><<<SEG_G, 256, 0, stream>>>(xu, rowptr_g, e_ug, buf, NG);
    gemm_mfma<true><<<GG, 256, 0, stream>>>(buf, WrugT[0], xg, WogT[0], b_ug[0], gA, NG, 128, 0, 1);
    gemm_mfma<false><<<GG, 256, 0, stream>>>(xg, WrguT[0], nullptr, nullptr, nullptr, buf, NG, 128, 0, 0);
    seg_sum16<256><<<SEG_U, 256, 0, stream>>>(buf, rowptr_u, e_gu, uA, NU);
    gemm_mfma<false><<<GU, 256, 0, stream>>>(xu, WouT[0], nullptr, nullptr, b_gu[0], uA, NU, 128, 1, 1);

    // ---- Layer 2 (K=256) ----  (uB is free now: tmp buffers dead after passB)
    seg_sum16<256><<<SEG_G, 256, 0, stream>>>(uA, rowptr_g, e_ug, buf, NG);
    gemm_mfma<true><<<GG, 256, 0, stream>>>(buf, WrugT[1], gA, WogT[1], b_ug[1], gB, NG, 256, 0, 1);
    gemm_mfma<false><<<GG, 256, 0, stream>>>(gA, WrguT[1], nullptr, nullptr, nullptr, buf, NG, 256, 0, 0);
    seg_sum16<256><<<SEG_U, 256, 0, stream>>>(buf, rowptr_u, e_gu, uB, NU);
    gemm_mfma<false><<<GU, 256, 0, stream>>>(uA, WouT[1], nullptr, nullptr, b_gu[1], uB, NU, 256, 1, 1);

    // ---- Layer 3 (K=256, no relu) ----
    seg_sum16<256><<<SEG_G, 256, 0, stream>>>(uB, rowptr_g, e_ug, buf, NG);
    gemm_mfma<true><<<GG, 256, 0, stream>>>(buf, WrugT[2], gB, WogT[2], b_ug[2], gA, NG, 256, 0, 0);
    gemm_mfma<false><<<GG, 256, 0, stream>>>(gB, WrguT[2], nullptr, nullptr, nullptr, buf, NG, 256, 0, 0);
    seg_sum16<256><<<SEG_U, 256, 0, stream>>>(buf, rowptr_u, e_gu, uA, NU);
    gemm_mfma<false><<<GU, 256, 0, stream>>>(uB, WouT[2], nullptr, nullptr, b_gu[2], uA, NU, 256, 1, 0);

    // ---- decode ----
    decode2<<<((SS + 1) / 2 + 3) / 4, 256, 0, stream>>>(uA, gA, score_row, score_col, out, SS);
}

// Round 6
// 1127.791 us; speedup vs baseline: 1.2635x; 1.2635x over previous
//
#include <hip/hip_runtime.h>

typedef unsigned short bf16_t;  // raw bf16 bits
typedef __attribute__((ext_vector_type(8))) short bf16x8;
typedef __attribute__((ext_vector_type(4))) float f32x4;

static constexpr int NU = 100000;   // users
static constexpr int NG = 20000;    // games
static constexpr int HD = 256;      // hidden
static constexpr int EE = 1000000;  // edges per direction
static constexpr int SS = 500000;   // score pairs

// CSR radix-partition geometry
static constexpr int SPAN = 1024;                     // rows per coarse bucket
static constexpr int BKT_G = (NG + SPAN - 1) / SPAN;  // 20
static constexpr int BKT_U = (NU + SPAN - 1) / SPAN;  // 98
static constexpr int PA_BLOCKS = 128;                 // blocks per direction
static constexpr int PA_CHUNK = (EE + PA_BLOCKS - 1) / PA_BLOCKS;
static constexpr int TILE = 4096;                     // edges per LDS sort tile

// ---------------- bf16 helpers ----------------
__device__ __forceinline__ float b2f(bf16_t u) {
    union { unsigned int i; float f; } x; x.i = ((unsigned int)u) << 16; return x.f;
}
__device__ __forceinline__ bf16_t f2b(float f) {
    union { float f; unsigned int i; } x; x.f = f;
    unsigned int r = x.i + 0x7FFF + ((x.i >> 16) & 1);  // RNE
    return (bf16_t)(r >> 16);
}

// accumulate 8 bf16 (packed in uint4) * w into acc[8]
__device__ __forceinline__ void accum8(float* acc, uint4 r, float w) {
    unsigned int u[4] = {r.x, r.y, r.z, r.w};
#pragma unroll
    for (int i = 0; i < 4; i++) {
        float lo = __uint_as_float(u[i] << 16);
        float hi = __uint_as_float(u[i] & 0xFFFF0000u);
        acc[2 * i]     = fmaf(w, lo, acc[2 * i]);
        acc[2 * i + 1] = fmaf(w, hi, acc[2 * i + 1]);
    }
}

// ---------------- preprocessing ----------------
__global__ void prep_feats(const float* __restrict__ xgame, const float* __restrict__ emb,
                           const float* __restrict__ xuser,
                           bf16_t* __restrict__ xg, bf16_t* __restrict__ xu,
                           int* __restrict__ gcg, int* __restrict__ gcu) {
    int id = blockIdx.x * 256 + threadIdx.x;
    if (id < BKT_G) gcg[id] = 0;
    if (id < BKT_U) gcu[id] = 0;
    const int ng4 = NG * 32;
    if (id < ng4) {
        int r = id >> 5, c = (id & 31) * 4;
        float4 v = (c < 64) ? *(const float4*)&xgame[(size_t)r * 64 + c]
                            : *(const float4*)&emb[(size_t)r * 64 + (c - 64)];
        ((ushort4*)xg)[id] = make_ushort4(f2b(v.x), f2b(v.y), f2b(v.z), f2b(v.w));
    } else {
        int j = id - ng4;
        if (j >= NU * 32) return;
        float4 v = ((const float4*)xuser)[j];
        ((ushort4*)xu)[j] = make_ushort4(f2b(v.x), f2b(v.y), f2b(v.z), f2b(v.w));
    }
}

struct WtArgs {
    const float* src[12];
    bf16_t* dst[12];
    int K[12];
    int off[13];
};
__global__ void wt_all(WtArgs a, int total) {
    int id = blockIdx.x * 256 + threadIdx.x;
    if (id >= total) return;
    int s = 0;
    while (id >= a.off[s + 1]) ++s;
    int local = id - a.off[s];
    int K = a.K[s];
    int k = local >> 8, n = local & 255;
    a.dst[s][(size_t)n * K + k] = f2b(a.src[s][local]);
}

// ---------------- CSR build: LDS-staged two-level radix partition ----------------
// coarse counts via LDS histogram (1 global atomic per bucket per block)
__global__ __launch_bounds__(256) void chisto(const int* __restrict__ dug,
                                              const int* __restrict__ dgu,
                                              int* __restrict__ gcg, int* __restrict__ gcu) {
    __shared__ int cnt[128];
    int blk = blockIdx.x;
    int dir = blk >> 7, lb = blk & 127;
    const int* dst = dir ? dgu : dug;
    int* gc = dir ? gcu : gcg;
    int B = dir ? BKT_U : BKT_G;
    int t = threadIdx.x;
    if (t < 128) cnt[t] = 0;
    __syncthreads();
    int beg = lb * PA_CHUNK, fin = min(EE, beg + PA_CHUNK);
    for (int i = beg + t; i < fin; i += 256)
        atomicAdd(&cnt[((unsigned)dst[i]) >> 10], 1);
    __syncthreads();
    if (t < B && cnt[t]) atomicAdd(&gc[t], cnt[t]);
}

// serial exclusive scans (tiny: 20 + 98); init gcur = base; rowptr tails
__global__ void scan_coarse(const int* __restrict__ gcg, const int* __restrict__ gcu,
                            int* __restrict__ baseg, int* __restrict__ baseu,
                            int* __restrict__ gcurg, int* __restrict__ gcuru,
                            int* __restrict__ rpg, int* __restrict__ rpu) {
    if (blockIdx.x == 0 && threadIdx.x == 0) {
        int run = 0;
        for (int i = 0; i < BKT_G; i++) { baseg[i] = run; gcurg[i] = run; run += gcg[i]; }
        rpg[NG] = EE;
    } else if (blockIdx.x == 1 && threadIdx.x == 0) {
        int run = 0;
        for (int i = 0; i < BKT_U; i++) { baseu[i] = run; gcuru[i] = run; run += gcu[i]; }
        rpu[NU] = EE;
    }
}

// LDS tile sort by coarse bucket, then bucket-contiguous burst copy to tmp
__global__ __launch_bounds__(256) void passA(
    const int* __restrict__ sug, const int* __restrict__ dug, const float* __restrict__ wug,
    const int* __restrict__ sgu, const int* __restrict__ dgu, const float* __restrict__ wgu,
    int* __restrict__ gcurg, int* __restrict__ gcuru,
    int2* __restrict__ tmpG, int2* __restrict__ tmpU) {
    __shared__ int cnt[128], sscan[128], gb[128];
    __shared__ unsigned short rankArr[TILE];
    __shared__ unsigned char sbkt[TILE];
    __shared__ int2 staged[TILE];
    int blk = blockIdx.x;
    int dir = blk >> 7, lb = blk & 127;
    const int* src = dir ? sgu : sug;
    const int* dst = dir ? dgu : dug;
    const float* w = dir ? wgu : wug;
    int* gcur = dir ? gcuru : gcurg;
    int2* tmp = dir ? tmpU : tmpG;
    int B = dir ? BKT_U : BKT_G;
    int t = threadIdx.x;
    int beg = lb * PA_CHUNK, fin = min(EE, beg + PA_CHUNK);
    for (int tb = beg; tb < fin; tb += TILE) {
        int n = min(TILE, fin - tb);
        if (t < 128) cnt[t] = 0;
        __syncthreads();
        for (int i = t; i < n; i += 256) {
            int bkt = ((unsigned)dst[tb + i]) >> 10;
            rankArr[i] = (unsigned short)atomicAdd(&cnt[bkt], 1);
        }
        __syncthreads();
        if (t == 0) {
            int run = 0;
            for (int i = 0; i < 128; i++) { sscan[i] = run; run += cnt[i]; }
        }
        __syncthreads();
        for (int i = t; i < n; i += 256) {
            unsigned d = (unsigned)dst[tb + i];
            int bkt = d >> 10;
            int pos = sscan[bkt] + rankArr[i];
            staged[pos] = make_int2(src[tb + i] | ((d & 1023u) << 17), __float_as_int(w[tb + i]));
            sbkt[pos] = (unsigned char)bkt;
        }
        __syncthreads();
        if (t < B && cnt[t]) gb[t] = atomicAdd(&gcur[t], cnt[t]);
        __syncthreads();
        for (int i = t; i < n; i += 256) {
            int bkt = sbkt[i];
            tmp[gb[bkt] + i - sscan[bkt]] = staged[i];  // contiguous per-bucket bursts
        }
        __syncthreads();
    }
}

// fine scatter within one bucket's L2-resident region; emits rowptr
__global__ __launch_bounds__(256) void passB(
    const int2* __restrict__ tmpG, const int2* __restrict__ tmpU,
    const int* __restrict__ baseg, const int* __restrict__ baseu,
    int* __restrict__ rpg, int* __restrict__ rpu,
    int2* __restrict__ eug, int2* __restrict__ egu) {
    __shared__ int hist[SPAN], excl[SPAN], sd[256];
    int b = blockIdx.x;
    const int2* tmp; const int* base; int* rowptr; int2* eout; int bkt, B, ntot;
    if (b < BKT_G) { tmp = tmpG; base = baseg; rowptr = rpg; eout = eug; bkt = b; B = BKT_G; ntot = NG; }
    else           { tmp = tmpU; base = baseu; rowptr = rpu; eout = egu; bkt = b - BKT_G; B = BKT_U; ntot = NU; }
    int start = base[bkt];
    int end = (bkt == B - 1) ? EE : base[bkt + 1];
    int row0 = bkt * SPAN;
    int t = threadIdx.x;
    for (int i = t; i < SPAN; i += 256) hist[i] = 0;
    __syncthreads();
    for (int i = start + t; i < end; i += 256)
        atomicAdd(&hist[((unsigned)tmp[i].x) >> 17], 1);
    __syncthreads();
    // exclusive scan of hist[0..1023]: 256 threads x 4
    int v[4]; int s = 0;
#pragma unroll
    for (int j = 0; j < 4; j++) { v[j] = hist[t * 4 + j]; s += v[j]; }
    sd[t] = s;
    __syncthreads();
    for (int off = 1; off < 256; off <<= 1) {
        int y = (t >= off) ? sd[t - off] : 0;
        __syncthreads();
        sd[t] += y;
        __syncthreads();
    }
    int run = sd[t] - s;
#pragma unroll
    for (int j = 0; j < 4; j++) { excl[t * 4 + j] = run; run += v[j]; }
    __syncthreads();
    for (int r = t; r < SPAN; r += 256) {
        int row = row0 + r;
        if (row < ntot) rowptr[row] = start + excl[r];
    }
    for (int i = t; i < SPAN; i += 256) hist[i] = 0;  // reuse as cursors
    __syncthreads();
    for (int i = start + t; i < end; i += 256) {
        int2 e = tmp[i];
        int dl = ((unsigned)e.x) >> 17;
        int pos = start + excl[dl] + atomicAdd(&hist[dl], 1);
        eout[pos] = make_int2(e.x & 0x1FFFF, e.y);
    }
}

// ---------------- segment sum: wave split into D/8-lane subgroups ----------------
template <int D>  // 128 or 256
__global__ __launch_bounds__(256) void seg_sum16(
    const bf16_t* __restrict__ feat, const int* __restrict__ rowptr,
    const int2* __restrict__ edges, bf16_t* __restrict__ out, int n_rows) {
    constexpr int LPE = D / 8;    // lanes per edge-row (16 B each)
    constexpr int EP = 64 / LPE;  // edges per batch
    constexpr int UN = 4;         // batches in flight
    int wid = (blockIdx.x * 256 + threadIdx.x) >> 6;
    int lane = threadIdx.x & 63;
    if (wid >= n_rows) return;
    int beg = rowptr[wid], end = rowptr[wid + 1];
    const int h = lane / LPE;
    const int cl = lane % LPE;
    const uint4* fb = (const uint4*)feat;
    float acc[8] = {};
    for (int eb = beg; eb < end; eb += UN * EP) {
        int2 ed[UN]; bool v[UN]; uint4 r[UN];
#pragma unroll
        for (int u = 0; u < UN; u++) {
            int e = eb + u * EP + h;
            v[u] = e < end;
            ed[u] = edges[v[u] ? e : beg];
        }
#pragma unroll
        for (int u = 0; u < UN; u++)
            r[u] = fb[(size_t)ed[u].x * (D / 8) + cl];
#pragma unroll
        for (int u = 0; u < UN; u++)
            accum8(acc, r[u], v[u] ? __int_as_float(ed[u].y) : 0.f);
    }
#pragma unroll
    for (int k = 0; k < 8; ++k) {
        acc[k] += __shfl_down(acc[k], 32, 64);
        if (LPE == 16) acc[k] += __shfl_down(acc[k], 16, 64);
    }
    if (lane < LPE) {
        uint4 o;
        o.x = (unsigned)f2b(acc[0]) | ((unsigned)f2b(acc[1]) << 16);
        o.y = (unsigned)f2b(acc[2]) | ((unsigned)f2b(acc[3]) << 16);
        o.z = (unsigned)f2b(acc[4]) | ((unsigned)f2b(acc[5]) << 16);
        o.w = (unsigned)f2b(acc[6]) | ((unsigned)f2b(acc[7]) << 16);
        ((uint4*)(out + (size_t)wid * D))[lane] = o;
    }
}

// ---------------- MFMA GEMM: C(bf16,[M,256]) = A1@W1 (+A2@W2) (+bias) (+C) (relu?) ----
template <bool TWOPASS>
__global__ __launch_bounds__(256) void gemm_mfma(
    const bf16_t* __restrict__ A1, const bf16_t* __restrict__ W1t,
    const bf16_t* __restrict__ A2, const bf16_t* __restrict__ W2t,
    const float* __restrict__ bias, bf16_t* __restrict__ C,
    int M, int K, int addc, int relu) {
    constexpr int LS = 40;
    __shared__ bf16_t As[128 * LS];
    __shared__ bf16_t Bs[128 * LS];
    const int t = threadIdx.x;
    const int lane = t & 63, wave = t >> 6;
    const int wm = (wave >> 1) * 64, wn = (wave & 1) * 64;
    const int rowBase = blockIdx.x * 128;
    const int colBase = blockIdx.y * 128;
    const int lm = lane & 15;
    const int quad = lane >> 4;
    f32x4 acc[4][4] = {};

    const int npass = TWOPASS ? 2 : 1;
    for (int pass = 0; pass < npass; ++pass) {
        const bf16_t* A = pass ? A2 : A1;
        const bf16_t* Wt = pass ? W2t : W1t;
        for (int k0 = 0; k0 < K; k0 += 32) {
#pragma unroll
            for (int i = 0; i < 2; ++i) {
                int li = t + i * 256;
                int r = li >> 2, c = (li & 3) * 8;
                int gm = rowBase + r;
                bf16x8 v = {};
                if (gm < M) v = *(const bf16x8*)&A[(size_t)gm * K + k0 + c];
                *(bf16x8*)&As[r * LS + c] = v;
            }
#pragma unroll
            for (int i = 0; i < 2; ++i) {
                int li = t + i * 256;
                int r = li >> 2, c = (li & 3) * 8;
                bf16x8 v = *(const bf16x8*)&Wt[(size_t)(colBase + r) * K + k0 + c];
                *(bf16x8*)&Bs[r * LS + c] = v;
            }
            __syncthreads();
            bf16x8 af[4], bfr[4];
#pragma unroll
            for (int i = 0; i < 4; ++i)
                af[i] = *(const bf16x8*)&As[(wm + i * 16 + lm) * LS + quad * 8];
#pragma unroll
            for (int j = 0; j < 4; ++j)
                bfr[j] = *(const bf16x8*)&Bs[(wn + j * 16 + lm) * LS + quad * 8];
#pragma unroll
            for (int i = 0; i < 4; ++i)
#pragma unroll
                for (int j = 0; j < 4; ++j)
                    acc[i][j] = __builtin_amdgcn_mfma_f32_16x16x32_bf16(af[i], bfr[j], acc[i][j], 0, 0, 0);
            __syncthreads();
        }
    }

#pragma unroll
    for (int j = 0; j < 4; ++j) {
        int col = colBase + wn + j * 16 + lm;
        float bj = bias ? bias[col] : 0.f;
#pragma unroll
        for (int i = 0; i < 4; ++i) {
            int row0 = rowBase + wm + i * 16 + quad * 4;
#pragma unroll
            for (int r = 0; r < 4; ++r) {
                int row = row0 + r;
                if (row >= M) continue;
                float v = acc[i][j][r] + bj;
                bf16_t* cp = &C[(size_t)row * HD + col];
                if (addc) v += b2f(*cp);
                if (relu) v = fmaxf(v, 0.f);
                *cp = f2b(v);
            }
        }
    }
}

// ---------------- decoder: 2 pairs per wave, 16 B loads ----------------
__global__ __launch_bounds__(256) void decode2(
    const bf16_t* __restrict__ u3, const bf16_t* __restrict__ g3,
    const int* __restrict__ row, const int* __restrict__ col,
    float* __restrict__ out, int S) {
    int wid = (blockIdx.x * 256 + threadIdx.x) >> 6;
    int lane = threadIdx.x & 63;
    int p = wid * 2 + (lane >> 5);
    int cl = lane & 31;
    if (p >= S) p = S - 1;  // tail lanes recompute last pair (benign dup store)
    int r = row[p], c = col[p];
    uint4 a = ((const uint4*)(u3 + (size_t)r * 256))[cl];
    uint4 b = ((const uint4*)(g3 + (size_t)c * 256))[cl];
    float s = 0.f;
    unsigned ua[4] = {a.x, a.y, a.z, a.w}, ub[4] = {b.x, b.y, b.z, b.w};
#pragma unroll
    for (int i = 0; i < 4; i++) {
        float alo = __uint_as_float(ua[i] << 16), ahi = __uint_as_float(ua[i] & 0xFFFF0000u);
        float blo = __uint_as_float(ub[i] << 16), bhi = __uint_as_float(ub[i] & 0xFFFF0000u);
        s = fmaf(alo, blo, s);
        s = fmaf(ahi, bhi, s);
    }
#pragma unroll
    for (int d = 16; d > 0; d >>= 1) s += __shfl_down(s, d, 64);
    if (cl == 0) out[p] = s;
}

extern "C" void kernel_launch(void* const* d_in, const int* in_sizes, int n_in,
                              void* d_out, int out_size, void* d_ws, size_t ws_size,
                              hipStream_t stream) {
    const float* x_user  = (const float*)d_in[0];
    const float* x_game  = (const float*)d_in[1];
    const float* emb_game= (const float*)d_in[2];
    const float* ew_ug   = (const float*)d_in[3];
    const float* ew_gu   = (const float*)d_in[4];
    const int* src_ug    = (const int*)d_in[5];
    const int* dst_ug    = (const int*)d_in[6];
    const int* src_gu    = (const int*)d_in[7];
    const int* dst_gu    = (const int*)d_in[8];
    const int* score_row = (const int*)d_in[9];
    const int* score_col = (const int*)d_in[10];
    const float* Wr_ug[3] = {(const float*)d_in[11], (const float*)d_in[17], (const float*)d_in[23]};
    const float* b_ug[3]  = {(const float*)d_in[12], (const float*)d_in[18], (const float*)d_in[24]};
    const float* Wo_g[3]  = {(const float*)d_in[13], (const float*)d_in[19], (const float*)d_in[25]};
    const float* Wr_gu[3] = {(const float*)d_in[14], (const float*)d_in[20], (const float*)d_in[26]};
    const float* b_gu[3]  = {(const float*)d_in[15], (const float*)d_in[21], (const float*)d_in[27]};
    const float* Wo_u[3]  = {(const float*)d_in[16], (const float*)d_in[22], (const float*)d_in[28]};
    float* out = (float*)d_out;
    (void)in_sizes; (void)n_in; (void)out_size;

    constexpr size_t WS_NEEDED = 183500000;
    if (ws_size < WS_NEEDED) return;  // clean fail, no OOB fault

    char* ws = (char*)d_ws;
    size_t off = 0;
    auto alloc = [&](size_t bytes) -> void* {
        void* p = ws + off;
        off += (bytes + 255) & ~(size_t)255;
        return p;
    };
    bf16_t* xg   = (bf16_t*)alloc((size_t)NG * 128 * 2);
    bf16_t* xu   = (bf16_t*)alloc((size_t)NU * 128 * 2);
    bf16_t* uA   = (bf16_t*)alloc((size_t)NU * HD * 2);
    bf16_t* uB   = (bf16_t*)alloc((size_t)NU * HD * 2);
    bf16_t* gA   = (bf16_t*)alloc((size_t)NG * HD * 2);
    bf16_t* gB   = (bf16_t*)alloc((size_t)NG * HD * 2);
    bf16_t* buf  = (bf16_t*)alloc((size_t)NG * HD * 2);
    int2*   e_ug = (int2*)  alloc((size_t)EE * 8);
    int2*   e_gu = (int2*)  alloc((size_t)EE * 8);
    bf16_t* WrugT[3], *WogT[3], *WrguT[3], *WouT[3];
    const int Ks[3] = {128, 256, 256};
    for (int l = 0; l < 3; ++l) {
        WrugT[l] = (bf16_t*)alloc((size_t)Ks[l] * HD * 2);
        WogT[l]  = (bf16_t*)alloc((size_t)Ks[l] * HD * 2);
        WrguT[l] = (bf16_t*)alloc((size_t)Ks[l] * HD * 2);
        WouT[l]  = (bf16_t*)alloc((size_t)Ks[l] * HD * 2);
    }
    int* rowptr_g = (int*)alloc((NG + 1) * 4);
    int* rowptr_u = (int*)alloc((NU + 1) * 4);
    int* gcnt_g   = (int*)alloc(BKT_G * 4);
    int* gcnt_u   = (int*)alloc(BKT_U * 4);
    int* base_g   = (int*)alloc(BKT_G * 4);
    int* base_u   = (int*)alloc(BKT_U * 4);
    int* gcur_g   = (int*)alloc(BKT_G * 4);
    int* gcur_u   = (int*)alloc(BKT_U * 4);
    // tmp partition buffers alias uB (dead until layer 2, after passB completes)
    int2* tmp_g = (int2*)uB;
    int2* tmp_u = tmp_g + EE;

    // ---- preprocessing ----
    {
        int n4 = NG * 32 + NU * 32;
        prep_feats<<<(n4 + 255) / 256, 256, 0, stream>>>(x_game, emb_game, x_user, xg, xu,
                                                         gcnt_g, gcnt_u);
        WtArgs wa;
        const float* srcs[12] = {Wr_ug[0], Wo_g[0], Wr_gu[0], Wo_u[0],
                                 Wr_ug[1], Wo_g[1], Wr_gu[1], Wo_u[1],
                                 Wr_ug[2], Wo_g[2], Wr_gu[2], Wo_u[2]};
        bf16_t* dsts[12] = {WrugT[0], WogT[0], WrguT[0], WouT[0],
                            WrugT[1], WogT[1], WrguT[1], WouT[1],
                            WrugT[2], WogT[2], WrguT[2], WouT[2]};
        int total = 0;
        for (int i = 0; i < 12; ++i) {
            wa.src[i] = srcs[i]; wa.dst[i] = dsts[i];
            wa.K[i] = Ks[i / 4]; wa.off[i] = total;
            total += Ks[i / 4] * HD;
        }
        wa.off[12] = total;
        wt_all<<<(total + 255) / 256, 256, 0, stream>>>(wa, total);
    }
    // ---- CSR build ----
    chisto<<<2 * PA_BLOCKS, 256, 0, stream>>>(dst_ug, dst_gu, gcnt_g, gcnt_u);
    scan_coarse<<<2, 64, 0, stream>>>(gcnt_g, gcnt_u, base_g, base_u, gcur_g, gcur_u,
                                      rowptr_g, rowptr_u);
    passA<<<2 * PA_BLOCKS, 256, 0, stream>>>(src_ug, dst_ug, ew_ug, src_gu, dst_gu, ew_gu,
                                             gcur_g, gcur_u, tmp_g, tmp_u);
    passB<<<BKT_G + BKT_U, 256, 0, stream>>>(tmp_g, tmp_u, base_g, base_u,
                                             rowptr_g, rowptr_u, e_ug, e_gu);

    const dim3 GG((NG + 127) / 128, 2), GU((NU + 127) / 128, 2);
    const int SEG_G = (NG + 3) / 4, SEG_U = (NU + 3) / 4;

    // ---- Layer 1 (K=128) ----
    seg_sum16<128><<<SEG_G, 256, 0, stream>>>(xu, rowptr_g, e_ug, buf, NG);
    gemm_mfma<true><<<GG, 256, 0, stream>>>(buf, WrugT[0], xg, WogT[0], b_ug[0], gA, NG, 128, 0, 1);
    gemm_mfma<false><<<GG, 256, 0, stream>>>(xg, WrguT[0], nullptr, nullptr, nullptr, buf, NG, 128, 0, 0);
    seg_sum16<256><<<SEG_U, 256, 0, stream>>>(buf, rowptr_u, e_gu, uA, NU);
    gemm_mfma<false><<<GU, 256, 0, stream>>>(xu, WouT[0], nullptr, nullptr, b_gu[0], uA, NU, 128, 1, 1);

    // ---- Layer 2 (K=256) ----  (uB free now: tmp buffers dead after passB)
    seg_sum16<256><<<SEG_G, 256, 0, stream>>>(uA, rowptr_g, e_ug, buf, NG);
    gemm_mfma<true><<<GG, 256, 0, stream>>>(buf, WrugT[1], gA, WogT[1], b_ug[1], gB, NG, 256, 0, 1);
    gemm_mfma<false><<<GG, 256, 0, stream>>>(gA, WrguT[1], nullptr, nullptr, nullptr, buf, NG, 256, 0, 0);
    seg_sum16<256><<<SEG_U, 256, 0, stream>>>(buf, rowptr_u, e_gu, uB, NU);
    gemm_mfma<false><<<GU, 256, 0, stream>>>(uA, WouT[1], nullptr, nullptr, b_gu[1], uB, NU, 256, 1, 1);

    // ---- Layer 3 (K=256, no relu) ----
    seg_sum16<256><<<SEG_G, 256, 0, stream>>>(uB, rowptr_g, e_ug, buf, NG);
    gemm_mfma<true><<<GG, 256, 0, stream>>>(buf, WrugT[2], gB, WogT[2], b_ug[2], gA, NG, 256, 0, 0);
    gemm_mfma<false><<<GG, 256, 0, stream>>>(gB, WrguT[2], nullptr, nullptr, nullptr, buf, NG, 256, 0, 0);
    seg_sum16<256><<<SEG_U, 256, 0, stream>>>(buf, rowptr_u, e_gu, uA, NU);
    gemm_mfma<false><<<GU, 256, 0, stream>>>(uB, WouT[2], nullptr, nullptr, b_gu[2], uA, NU, 256, 1, 0);

    // ---- decode ----
    decode2<<<((SS + 1) / 2 + 3) / 4, 256, 0, stream>>>(uA, gA, score_row, score_col, out, SS);
}

// Round 7
// 1099.783 us; speedup vs baseline: 1.2957x; 1.0255x over previous
//
#include <hip/hip_runtime.h>

typedef unsigned short bf16_t;  // raw bf16 bits
typedef __attribute__((ext_vector_type(8))) short bf16x8;
typedef __attribute__((ext_vector_type(4))) float f32x4;

static constexpr int NU = 100000;   // users
static constexpr int NG = 20000;    // games
static constexpr int HD = 256;      // hidden
static constexpr int EE = 1000000;  // edges per direction
static constexpr int SS = 500000;   // score pairs

// CSR radix-partition geometry
static constexpr int SPAN = 1024;                     // rows per coarse bucket
static constexpr int BKT_G = (NG + SPAN - 1) / SPAN;  // 20
static constexpr int BKT_U = (NU + SPAN - 1) / SPAN;  // 98
static constexpr int PA_BLOCKS = 256;                 // blocks per direction
static constexpr int PA_CHUNK = (EE + PA_BLOCKS - 1) / PA_BLOCKS;  // 3907
static constexpr int TILE = 4096;                     // edges per LDS sort tile
static constexpr int NSC_G = (NG + 1023) / 1024;      // 20 scan blocks
static constexpr int NSC_U = (NU + 1023) / 1024;      // 98 scan blocks

// ---------------- bf16 helpers ----------------
__device__ __forceinline__ float b2f(bf16_t u) {
    union { unsigned int i; float f; } x; x.i = ((unsigned int)u) << 16; return x.f;
}
__device__ __forceinline__ bf16_t f2b(float f) {
    union { float f; unsigned int i; } x; x.f = f;
    unsigned int r = x.i + 0x7FFF + ((x.i >> 16) & 1);  // RNE
    return (bf16_t)(r >> 16);
}

// accumulate 8 bf16 (packed in uint4) * w into acc[8]
__device__ __forceinline__ void accum8(float* acc, uint4 r, float w) {
    unsigned int u[4] = {r.x, r.y, r.z, r.w};
#pragma unroll
    for (int i = 0; i < 4; i++) {
        float lo = __uint_as_float(u[i] << 16);
        float hi = __uint_as_float(u[i] & 0xFFFF0000u);
        acc[2 * i]     = fmaf(w, lo, acc[2 * i]);
        acc[2 * i + 1] = fmaf(w, hi, acc[2 * i + 1]);
    }
}

// ---------------- preprocessing ----------------
__global__ void prep_feats(const float* __restrict__ xgame, const float* __restrict__ emb,
                           const float* __restrict__ xuser,
                           bf16_t* __restrict__ xg, bf16_t* __restrict__ xu,
                           int* __restrict__ gcg, int* __restrict__ gcu) {
    int id = blockIdx.x * 256 + threadIdx.x;
    if (id < BKT_G) gcg[id] = 0;
    if (id < BKT_U) gcu[id] = 0;
    const int ng4 = NG * 32;
    if (id < ng4) {
        int r = id >> 5, c = (id & 31) * 4;
        float4 v = (c < 64) ? *(const float4*)&xgame[(size_t)r * 64 + c]
                            : *(const float4*)&emb[(size_t)r * 64 + (c - 64)];
        ((ushort4*)xg)[id] = make_ushort4(f2b(v.x), f2b(v.y), f2b(v.z), f2b(v.w));
    } else {
        int j = id - ng4;
        if (j >= NU * 32) return;
        float4 v = ((const float4*)xuser)[j];
        ((ushort4*)xu)[j] = make_ushort4(f2b(v.x), f2b(v.y), f2b(v.z), f2b(v.w));
    }
}

struct WtArgs {
    const float* src[12];
    bf16_t* dst[12];
    int K[12];
    int off[13];
};
__global__ void wt_all(WtArgs a, int total) {
    int id = blockIdx.x * 256 + threadIdx.x;
    if (id >= total) return;
    int s = 0;
    while (id >= a.off[s + 1]) ++s;
    int local = id - a.off[s];
    int K = a.K[s];
    int k = local >> 8, n = local & 255;
    a.dst[s][(size_t)n * K + k] = f2b(a.src[s][local]);
}

// ---------------- CSR build: LDS-staged two-level radix partition ----------------
// coarse counts via LDS histogram; also zeroes rowcnt arrays
__global__ __launch_bounds__(256) void chisto(const int* __restrict__ dug,
                                              const int* __restrict__ dgu,
                                              int* __restrict__ gcg, int* __restrict__ gcu,
                                              int* __restrict__ rcg, int* __restrict__ rcu) {
    __shared__ int cnt[128];
    int blk = blockIdx.x;
    int gid = blk * 256 + threadIdx.x;  // 512*256 = 131072 >= NG+NU
    if (gid < NG) rcg[gid] = 0;
    else if (gid < NG + NU) rcu[gid - NG] = 0;
    int dir = blk >> 8, lb = blk & 255;
    const int* dst = dir ? dgu : dug;
    int* gc = dir ? gcu : gcg;
    int B = dir ? BKT_U : BKT_G;
    int t = threadIdx.x;
    if (t < 128) cnt[t] = 0;
    __syncthreads();
    int beg = lb * PA_CHUNK, fin = min(EE, beg + PA_CHUNK);
    for (int i = beg + t; i < fin; i += 256)
        atomicAdd(&cnt[((unsigned)dst[i]) >> 10], 1);
    __syncthreads();
    if (t < B && cnt[t]) atomicAdd(&gc[t], cnt[t]);
}

// serial exclusive scans over coarse buckets (tiny: 20 + 98)
__global__ void scan_coarse(const int* __restrict__ gcg, const int* __restrict__ gcu,
                            int* __restrict__ baseg, int* __restrict__ baseu,
                            int* __restrict__ gcurg, int* __restrict__ gcuru,
                            int* __restrict__ rpg, int* __restrict__ rpu) {
    if (blockIdx.x == 0 && threadIdx.x == 0) {
        int run = 0;
        for (int i = 0; i < BKT_G; i++) { baseg[i] = run; gcurg[i] = run; run += gcg[i]; }
        rpg[NG] = EE;
    } else if (blockIdx.x == 1 && threadIdx.x == 0) {
        int run = 0;
        for (int i = 0; i < BKT_U; i++) { baseu[i] = run; gcuru[i] = run; run += gcu[i]; }
        rpu[NU] = EE;
    }
}

// LDS tile sort by coarse bucket, then bucket-contiguous burst copy to tmp
__global__ __launch_bounds__(256) void passA(
    const int* __restrict__ sug, const int* __restrict__ dug, const float* __restrict__ wug,
    const int* __restrict__ sgu, const int* __restrict__ dgu, const float* __restrict__ wgu,
    int* __restrict__ gcurg, int* __restrict__ gcuru,
    int2* __restrict__ tmpG, int2* __restrict__ tmpU) {
    __shared__ int cnt[128], sscan[128], gb[128];
    __shared__ unsigned short rankArr[TILE];
    __shared__ unsigned char sbkt[TILE];
    __shared__ int2 staged[TILE];
    int blk = blockIdx.x;
    int dir = blk >> 8, lb = blk & 255;
    const int* src = dir ? sgu : sug;
    const int* dst = dir ? dgu : dug;
    const float* w = dir ? wgu : wug;
    int* gcur = dir ? gcuru : gcurg;
    int2* tmp = dir ? tmpU : tmpG;
    int B = dir ? BKT_U : BKT_G;
    int t = threadIdx.x;
    int beg = lb * PA_CHUNK, fin = min(EE, beg + PA_CHUNK);
    for (int tb = beg; tb < fin; tb += TILE) {
        int n = min(TILE, fin - tb);
        if (t < 128) cnt[t] = 0;
        __syncthreads();
        for (int i = t; i < n; i += 256) {
            int bkt = ((unsigned)dst[tb + i]) >> 10;
            rankArr[i] = (unsigned short)atomicAdd(&cnt[bkt], 1);
        }
        __syncthreads();
        if (t == 0) {
            int run = 0;
            for (int i = 0; i < 128; i++) { sscan[i] = run; run += cnt[i]; }
        }
        __syncthreads();
        for (int i = t; i < n; i += 256) {
            unsigned d = (unsigned)dst[tb + i];
            int bkt = d >> 10;
            int pos = sscan[bkt] + rankArr[i];
            staged[pos] = make_int2(src[tb + i] | ((d & 1023u) << 17), __float_as_int(w[tb + i]));
            sbkt[pos] = (unsigned char)bkt;
        }
        __syncthreads();
        if (t < B && cnt[t]) gb[t] = atomicAdd(&gcur[t], cnt[t]);
        __syncthreads();
        for (int i = t; i < n; i += 256) {
            int bkt = sbkt[i];
            tmp[gb[bkt] + i - sscan[bkt]] = staged[i];  // contiguous per-bucket bursts
        }
        __syncthreads();
    }
}

// ---- fine phase, parallel: bucket x 8 slices ----
__device__ __forceinline__ void slice_bounds(const int* base, int bkt, int B, int sl,
                                             int& s0, int& s1) {
    int start = base[bkt];
    int end = (bkt == B - 1) ? EE : base[bkt + 1];
    int len = end - start;
    s0 = start + (int)(((long long)len * sl) >> 3);
    s1 = start + (int)(((long long)len * (sl + 1)) >> 3);
}

__global__ __launch_bounds__(256) void passB_hist(
    const int2* __restrict__ tmpG, const int2* __restrict__ tmpU,
    const int* __restrict__ baseg, const int* __restrict__ baseu,
    int* __restrict__ rcg, int* __restrict__ rcu) {
    __shared__ int hist[SPAN];
    int b = blockIdx.x >> 3, sl = blockIdx.x & 7;
    const int2* tmp; const int* base; int* rowcnt; int bkt, B;
    if (b < BKT_G) { tmp = tmpG; base = baseg; rowcnt = rcg; bkt = b; B = BKT_G; }
    else           { tmp = tmpU; base = baseu; rowcnt = rcu; bkt = b - BKT_G; B = BKT_U; }
    int s0, s1;
    slice_bounds(base, bkt, B, sl, s0, s1);
    int t = threadIdx.x;
    for (int i = t; i < SPAN; i += 256) hist[i] = 0;
    __syncthreads();
    for (int i = s0 + t; i < s1; i += 256)
        atomicAdd(&hist[((unsigned)tmp[i].x) >> 17], 1);
    __syncthreads();
    int row0 = bkt * SPAN;
    for (int i = t; i < SPAN; i += 256)
        if (hist[i]) atomicAdd(&rowcnt[row0 + i], hist[i]);
}

// exclusive scan rowcnt -> rowptr (1024 elems/block); zero cursors
__device__ __forceinline__ void scan1_body(const int* cnt, int* rowptr, int* bsum,
                                           int* cur, int n, int lb) {
    __shared__ int sd[256];
    int t = threadIdx.x;
    int base = lb * 1024;
    int v[4]; int s = 0;
#pragma unroll
    for (int i = 0; i < 4; i++) {
        int idx = base + t * 4 + i;
        v[i] = (idx < n) ? cnt[idx] : 0;
        if (idx < n) cur[idx] = 0;
        s += v[i];
    }
    sd[t] = s;
    __syncthreads();
    for (int off = 1; off < 256; off <<= 1) {
        int y = (t >= off) ? sd[t - off] : 0;
        __syncthreads();
        sd[t] += y;
        __syncthreads();
    }
    int run = sd[t] - s;
#pragma unroll
    for (int i = 0; i < 4; i++) {
        int idx = base + t * 4 + i;
        if (idx < n) rowptr[idx] = run;
        run += v[i];
    }
    if (t == 255) bsum[lb] = sd[255];
}

__global__ void scan1b(const int* __restrict__ cg, int* __restrict__ rpg, int* __restrict__ bsg,
                       int* __restrict__ curg,
                       const int* __restrict__ cu, int* __restrict__ rpu, int* __restrict__ bsu,
                       int* __restrict__ curu) {
    int b = blockIdx.x;
    if (b < NSC_G) scan1_body(cg, rpg, bsg, curg, NG, b);
    else           scan1_body(cu, rpu, bsu, curu, NU, b - NSC_G);
}

__global__ void scan2b(int* __restrict__ bsg, int* __restrict__ bsu) {
    if (blockIdx.x != 0) return;
    if (threadIdx.x == 0) {
        int run = 0;
        for (int i = 0; i < NSC_G; i++) { int v = bsg[i]; bsg[i] = run; run += v; }
    } else if (threadIdx.x == 1) {
        int run = 0;
        for (int i = 0; i < NSC_U; i++) { int v = bsu[i]; bsu[i] = run; run += v; }
    }
}

__global__ void scan3b(int* __restrict__ rpg, const int* __restrict__ bsg,
                       int* __restrict__ rpu, const int* __restrict__ bsu) {
    int b = blockIdx.x;
    int t = threadIdx.x;
    if (b < NSC_G) {
        int add = bsg[b];
        int base = b * 1024;
#pragma unroll
        for (int i = 0; i < 4; i++) {
            int idx = base + t * 4 + i;
            if (idx < NG) rpg[idx] += add;
        }
    } else {
        int add = bsu[b - NSC_G];
        int base = (b - NSC_G) * 1024;
#pragma unroll
        for (int i = 0; i < 4; i++) {
            int idx = base + t * 4 + i;
            if (idx < NU) rpu[idx] += add;
        }
    }
}

__global__ __launch_bounds__(256) void passB_scat(
    const int2* __restrict__ tmpG, const int2* __restrict__ tmpU,
    const int* __restrict__ baseg, const int* __restrict__ baseu,
    const int* __restrict__ rpg, const int* __restrict__ rpu,
    int* __restrict__ curg, int* __restrict__ curu,
    int2* __restrict__ eug, int2* __restrict__ egu) {
    int b = blockIdx.x >> 3, sl = blockIdx.x & 7;
    const int2* tmp; const int* base; const int* rowptr; int* cur; int2* eout; int bkt, B;
    if (b < BKT_G) { tmp = tmpG; base = baseg; rowptr = rpg; cur = curg; eout = eug; bkt = b; B = BKT_G; }
    else           { tmp = tmpU; base = baseu; rowptr = rpu; cur = curu; eout = egu; bkt = b - BKT_G; B = BKT_U; }
    int s0, s1;
    slice_bounds(base, bkt, B, sl, s0, s1);
    int row0 = bkt * SPAN;
    for (int i = s0 + threadIdx.x; i < s1; i += 256) {
        int2 e = tmp[i];
        int row = row0 + (int)(((unsigned)e.x) >> 17);
        int pos = rowptr[row] + atomicAdd(&cur[row], 1);
        eout[pos] = make_int2(e.x & 0x1FFFF, e.y);
    }
}

// ---------------- segment sum: wave split into D/8-lane subgroups ----------------
template <int D>  // 128 or 256
__global__ __launch_bounds__(256) void seg_sum16(
    const bf16_t* __restrict__ feat, const int* __restrict__ rowptr,
    const int2* __restrict__ edges, bf16_t* __restrict__ out, int n_rows) {
    constexpr int LPE = D / 8;    // lanes per edge-row (16 B each)
    constexpr int EP = 64 / LPE;  // edges per batch
    constexpr int UN = 4;         // batches in flight
    int wid = (blockIdx.x * 256 + threadIdx.x) >> 6;
    int lane = threadIdx.x & 63;
    if (wid >= n_rows) return;
    int beg = rowptr[wid], end = rowptr[wid + 1];
    const int h = lane / LPE;
    const int cl = lane % LPE;
    const uint4* fb = (const uint4*)feat;
    float acc[8] = {};
    for (int eb = beg; eb < end; eb += UN * EP) {
        int2 ed[UN]; bool v[UN]; uint4 r[UN];
#pragma unroll
        for (int u = 0; u < UN; u++) {
            int e = eb + u * EP + h;
            v[u] = e < end;
            ed[u] = edges[v[u] ? e : beg];
        }
#pragma unroll
        for (int u = 0; u < UN; u++)
            r[u] = fb[(size_t)ed[u].x * (D / 8) + cl];
#pragma unroll
        for (int u = 0; u < UN; u++)
            accum8(acc, r[u], v[u] ? __int_as_float(ed[u].y) : 0.f);
    }
#pragma unroll
    for (int k = 0; k < 8; ++k) {
        acc[k] += __shfl_down(acc[k], 32, 64);
        if (LPE == 16) acc[k] += __shfl_down(acc[k], 16, 64);
    }
    if (lane < LPE) {
        uint4 o;
        o.x = (unsigned)f2b(acc[0]) | ((unsigned)f2b(acc[1]) << 16);
        o.y = (unsigned)f2b(acc[2]) | ((unsigned)f2b(acc[3]) << 16);
        o.z = (unsigned)f2b(acc[4]) | ((unsigned)f2b(acc[5]) << 16);
        o.w = (unsigned)f2b(acc[6]) | ((unsigned)f2b(acc[7]) << 16);
        ((uint4*)(out + (size_t)wid * D))[lane] = o;
    }
}

// ---------------- MFMA GEMM: C(bf16,[M,256]) = A1@W1 (+A2@W2) (+bias) (+C) (relu?) ----
template <bool TWOPASS>
__global__ __launch_bounds__(256) void gemm_mfma(
    const bf16_t* __restrict__ A1, const bf16_t* __restrict__ W1t,
    const bf16_t* __restrict__ A2, const bf16_t* __restrict__ W2t,
    const float* __restrict__ bias, bf16_t* __restrict__ C,
    int M, int K, int addc, int relu) {
    constexpr int LS = 40;
    __shared__ bf16_t As[128 * LS];
    __shared__ bf16_t Bs[128 * LS];
    const int t = threadIdx.x;
    const int lane = t & 63, wave = t >> 6;
    const int wm = (wave >> 1) * 64, wn = (wave & 1) * 64;
    const int rowBase = blockIdx.x * 128;
    const int colBase = blockIdx.y * 128;
    const int lm = lane & 15;
    const int quad = lane >> 4;
    f32x4 acc[4][4] = {};

    const int npass = TWOPASS ? 2 : 1;
    for (int pass = 0; pass < npass; ++pass) {
        const bf16_t* A = pass ? A2 : A1;
        const bf16_t* Wt = pass ? W2t : W1t;
        for (int k0 = 0; k0 < K; k0 += 32) {
#pragma unroll
            for (int i = 0; i < 2; ++i) {
                int li = t + i * 256;
                int r = li >> 2, c = (li & 3) * 8;
                int gm = rowBase + r;
                bf16x8 v = {};
                if (gm < M) v = *(const bf16x8*)&A[(size_t)gm * K + k0 + c];
                *(bf16x8*)&As[r * LS + c] = v;
            }
#pragma unroll
            for (int i = 0; i < 2; ++i) {
                int li = t + i * 256;
                int r = li >> 2, c = (li & 3) * 8;
                bf16x8 v = *(const bf16x8*)&Wt[(size_t)(colBase + r) * K + k0 + c];
                *(bf16x8*)&Bs[r * LS + c] = v;
            }
            __syncthreads();
            bf16x8 af[4], bfr[4];
#pragma unroll
            for (int i = 0; i < 4; ++i)
                af[i] = *(const bf16x8*)&As[(wm + i * 16 + lm) * LS + quad * 8];
#pragma unroll
            for (int j = 0; j < 4; ++j)
                bfr[j] = *(const bf16x8*)&Bs[(wn + j * 16 + lm) * LS + quad * 8];
#pragma unroll
            for (int i = 0; i < 4; ++i)
#pragma unroll
                for (int j = 0; j < 4; ++j)
                    acc[i][j] = __builtin_amdgcn_mfma_f32_16x16x32_bf16(af[i], bfr[j], acc[i][j], 0, 0, 0);
            __syncthreads();
        }
    }

#pragma unroll
    for (int j = 0; j < 4; ++j) {
        int col = colBase + wn + j * 16 + lm;
        float bj = bias ? bias[col] : 0.f;
#pragma unroll
        for (int i = 0; i < 4; ++i) {
            int row0 = rowBase + wm + i * 16 + quad * 4;
#pragma unroll
            for (int r = 0; r < 4; ++r) {
                int row = row0 + r;
                if (row >= M) continue;
                float v = acc[i][j][r] + bj;
                bf16_t* cp = &C[(size_t)row * HD + col];
                if (addc) v += b2f(*cp);
                if (relu) v = fmaxf(v, 0.f);
                *cp = f2b(v);
            }
        }
    }
}

// ---------------- decoder: 2 pairs per wave, 16 B loads ----------------
__global__ __launch_bounds__(256) void decode2(
    const bf16_t* __restrict__ u3, const bf16_t* __restrict__ g3,
    const int* __restrict__ row, const int* __restrict__ col,
    float* __restrict__ out, int S) {
    int wid = (blockIdx.x * 256 + threadIdx.x) >> 6;
    int lane = threadIdx.x & 63;
    int p = wid * 2 + (lane >> 5);
    int cl = lane & 31;
    if (p >= S) p = S - 1;  // tail lanes recompute last pair (benign dup store)
    int r = row[p], c = col[p];
    uint4 a = ((const uint4*)(u3 + (size_t)r * 256))[cl];
    uint4 b = ((const uint4*)(g3 + (size_t)c * 256))[cl];
    float s = 0.f;
    unsigned ua[4] = {a.x, a.y, a.z, a.w}, ub[4] = {b.x, b.y, b.z, b.w};
#pragma unroll
    for (int i = 0; i < 4; i++) {
        float alo = __uint_as_float(ua[i] << 16), ahi = __uint_as_float(ua[i] & 0xFFFF0000u);
        float blo = __uint_as_float(ub[i] << 16), bhi = __uint_as_float(ub[i] & 0xFFFF0000u);
        s = fmaf(alo, blo, s);
        s = fmaf(ahi, bhi, s);
    }
#pragma unroll
    for (int d = 16; d > 0; d >>= 1) s += __shfl_down(s, d, 64);
    if (cl == 0) out[p] = s;
}

extern "C" void kernel_launch(void* const* d_in, const int* in_sizes, int n_in,
                              void* d_out, int out_size, void* d_ws, size_t ws_size,
                              hipStream_t stream) {
    const float* x_user  = (const float*)d_in[0];
    const float* x_game  = (const float*)d_in[1];
    const float* emb_game= (const float*)d_in[2];
    const float* ew_ug   = (const float*)d_in[3];
    const float* ew_gu   = (const float*)d_in[4];
    const int* src_ug    = (const int*)d_in[5];
    const int* dst_ug    = (const int*)d_in[6];
    const int* src_gu    = (const int*)d_in[7];
    const int* dst_gu    = (const int*)d_in[8];
    const int* score_row = (const int*)d_in[9];
    const int* score_col = (const int*)d_in[10];
    const float* Wr_ug[3] = {(const float*)d_in[11], (const float*)d_in[17], (const float*)d_in[23]};
    const float* b_ug[3]  = {(const float*)d_in[12], (const float*)d_in[18], (const float*)d_in[24]};
    const float* Wo_g[3]  = {(const float*)d_in[13], (const float*)d_in[19], (const float*)d_in[25]};
    const float* Wr_gu[3] = {(const float*)d_in[14], (const float*)d_in[20], (const float*)d_in[26]};
    const float* b_gu[3]  = {(const float*)d_in[15], (const float*)d_in[21], (const float*)d_in[27]};
    const float* Wo_u[3]  = {(const float*)d_in[16], (const float*)d_in[22], (const float*)d_in[28]};
    float* out = (float*)d_out;
    (void)in_sizes; (void)n_in; (void)out_size;

    constexpr size_t WS_NEEDED = 183500000;
    if (ws_size < WS_NEEDED) return;  // clean fail, no OOB fault

    char* ws = (char*)d_ws;
    size_t off = 0;
    auto alloc = [&](size_t bytes) -> void* {
        void* p = ws + off;
        off += (bytes + 255) & ~(size_t)255;
        return p;
    };
    bf16_t* xg   = (bf16_t*)alloc((size_t)NG * 128 * 2);
    bf16_t* xu   = (bf16_t*)alloc((size_t)NU * 128 * 2);
    bf16_t* uA   = (bf16_t*)alloc((size_t)NU * HD * 2);
    bf16_t* uB   = (bf16_t*)alloc((size_t)NU * HD * 2);
    bf16_t* gA   = (bf16_t*)alloc((size_t)NG * HD * 2);
    bf16_t* gB   = (bf16_t*)alloc((size_t)NG * HD * 2);
    bf16_t* buf  = (bf16_t*)alloc((size_t)NG * HD * 2);
    int2*   e_ug = (int2*)  alloc((size_t)EE * 8);
    int2*   e_gu = (int2*)  alloc((size_t)EE * 8);
    bf16_t* WrugT[3], *WogT[3], *WrguT[3], *WouT[3];
    const int Ks[3] = {128, 256, 256};
    for (int l = 0; l < 3; ++l) {
        WrugT[l] = (bf16_t*)alloc((size_t)Ks[l] * HD * 2);
        WogT[l]  = (bf16_t*)alloc((size_t)Ks[l] * HD * 2);
        WrguT[l] = (bf16_t*)alloc((size_t)Ks[l] * HD * 2);
        WouT[l]  = (bf16_t*)alloc((size_t)Ks[l] * HD * 2);
    }
    int* rowptr_g = (int*)alloc((NG + 1) * 4);
    int* rowptr_u = (int*)alloc((NU + 1) * 4);
    int* rowcnt_g = (int*)alloc(NG * 4);
    int* rowcnt_u = (int*)alloc(NU * 4);
    int* rowcur_g = (int*)alloc(NG * 4);
    int* rowcur_u = (int*)alloc(NU * 4);
    int* gcnt_g   = (int*)alloc(BKT_G * 4);
    int* gcnt_u   = (int*)alloc(BKT_U * 4);
    int* base_g   = (int*)alloc(BKT_G * 4);
    int* base_u   = (int*)alloc(BKT_U * 4);
    int* gcur_g   = (int*)alloc(BKT_G * 4);
    int* gcur_u   = (int*)alloc(BKT_U * 4);
    int* bsum_g   = (int*)alloc(NSC_G * 4);
    int* bsum_u   = (int*)alloc(NSC_U * 4);
    // tmp partition buffers alias uB (dead until layer 2, after passB_scat completes)
    int2* tmp_g = (int2*)uB;
    int2* tmp_u = tmp_g + EE;

    // ---- preprocessing ----
    {
        int n4 = NG * 32 + NU * 32;
        prep_feats<<<(n4 + 255) / 256, 256, 0, stream>>>(x_game, emb_game, x_user, xg, xu,
                                                         gcnt_g, gcnt_u);
        WtArgs wa;
        const float* srcs[12] = {Wr_ug[0], Wo_g[0], Wr_gu[0], Wo_u[0],
                                 Wr_ug[1], Wo_g[1], Wr_gu[1], Wo_u[1],
                                 Wr_ug[2], Wo_g[2], Wr_gu[2], Wo_u[2]};
        bf16_t* dsts[12] = {WrugT[0], WogT[0], WrguT[0], WouT[0],
                            WrugT[1], WogT[1], WrguT[1], WouT[1],
                            WrugT[2], WogT[2], WrguT[2], WouT[2]};
        int total = 0;
        for (int i = 0; i < 12; ++i) {
            wa.src[i] = srcs[i]; wa.dst[i] = dsts[i];
            wa.K[i] = Ks[i / 4]; wa.off[i] = total;
            total += Ks[i / 4] * HD;
        }
        wa.off[12] = total;
        wt_all<<<(total + 255) / 256, 256, 0, stream>>>(wa, total);
    }
    // ---- CSR build ----
    chisto<<<2 * PA_BLOCKS, 256, 0, stream>>>(dst_ug, dst_gu, gcnt_g, gcnt_u,
                                              rowcnt_g, rowcnt_u);
    scan_coarse<<<2, 64, 0, stream>>>(gcnt_g, gcnt_u, base_g, base_u, gcur_g, gcur_u,
                                      rowptr_g, rowptr_u);
    passA<<<2 * PA_BLOCKS, 256, 0, stream>>>(src_ug, dst_ug, ew_ug, src_gu, dst_gu, ew_gu,
                                             gcur_g, gcur_u, tmp_g, tmp_u);
    passB_hist<<<(BKT_G + BKT_U) * 8, 256, 0, stream>>>(tmp_g, tmp_u, base_g, base_u,
                                                        rowcnt_g, rowcnt_u);
    scan1b<<<NSC_G + NSC_U, 256, 0, stream>>>(rowcnt_g, rowptr_g, bsum_g, rowcur_g,
                                              rowcnt_u, rowptr_u, bsum_u, rowcur_u);
    scan2b<<<1, 64, 0, stream>>>(bsum_g, bsum_u);
    scan3b<<<NSC_G + NSC_U, 256, 0, stream>>>(rowptr_g, bsum_g, rowptr_u, bsum_u);
    passB_scat<<<(BKT_G + BKT_U) * 8, 256, 0, stream>>>(tmp_g, tmp_u, base_g, base_u,
                                                        rowptr_g, rowptr_u,
                                                        rowcur_g, rowcur_u, e_ug, e_gu);

    const dim3 GG((NG + 127) / 128, 2), GU((NU + 127) / 128, 2);
    const int SEG_G = (NG + 3) / 4, SEG_U = (NU + 3) / 4;

    // ---- Layer 1 (K=128) ----
    seg_sum16<128><<<SEG_G, 256, 0, stream>>>(xu, rowptr_g, e_ug, buf, NG);
    gemm_mfma<true><<<GG, 256, 0, stream>>>(buf, WrugT[0], xg, WogT[0], b_ug[0], gA, NG, 128, 0, 1);
    gemm_mfma<false><<<GG, 256, 0, stream>>>(xg, WrguT[0], nullptr, nullptr, nullptr, buf, NG, 128, 0, 0);
    seg_sum16<256><<<SEG_U, 256, 0, stream>>>(buf, rowptr_u, e_gu, uA, NU);
    gemm_mfma<false><<<GU, 256, 0, stream>>>(xu, WouT[0], nullptr, nullptr, b_gu[0], uA, NU, 128, 1, 1);

    // ---- Layer 2 (K=256) ----  (uB free now: tmp buffers dead after passB_scat)
    seg_sum16<256><<<SEG_G, 256, 0, stream>>>(uA, rowptr_g, e_ug, buf, NG);
    gemm_mfma<true><<<GG, 256, 0, stream>>>(buf, WrugT[1], gA, WogT[1], b_ug[1], gB, NG, 256, 0, 1);
    gemm_mfma<false><<<GG, 256, 0, stream>>>(gA, WrguT[1], nullptr, nullptr, nullptr, buf, NG, 256, 0, 0);
    seg_sum16<256><<<SEG_U, 256, 0, stream>>>(buf, rowptr_u, e_gu, uB, NU);
    gemm_mfma<false><<<GU, 256, 0, stream>>>(uA, WouT[1], nullptr, nullptr, b_gu[1], uB, NU, 256, 1, 1);

    // ---- Layer 3 (K=256, no relu) ----
    seg_sum16<256><<<SEG_G, 256, 0, stream>>>(uB, rowptr_g, e_ug, buf, NG);
    gemm_mfma<true><<<GG, 256, 0, stream>>>(buf, WrugT[2], gB, WogT[2], b_ug[2], gA, NG, 256, 0, 0);
    gemm_mfma<false><<<GG, 256, 0, stream>>>(gB, WrguT[2], nullptr, nullptr, nullptr, buf, NG, 256, 0, 0);
    seg_sum16<256><<<SEG_U, 256, 0, stream>>>(buf, rowptr_u, e_gu, uA, NU);
    gemm_mfma<false><<<GU, 256, 0, stream>>>(uB, WouT[2], nullptr, nullptr, b_gu[2], uA, NU, 256, 1, 0);

    // ---- decode ----
    decode2<<<((SS + 1) / 2 + 3) / 4, 256, 0, stream>>>(uA, gA, score_row, score_col, out, SS);
}

// Round 8
// 983.532 us; speedup vs baseline: 1.4489x; 1.1182x over previous
//
#include <hip/hip_runtime.h>

typedef unsigned short bf16_t;  // raw bf16 bits
typedef __attribute__((ext_vector_type(8))) short bf16x8;
typedef __attribute__((ext_vector_type(4))) float f32x4;

static constexpr int NU = 100000;   // users
static constexpr int NG = 20000;    // games
static constexpr int HD = 256;      // hidden
static constexpr int EE = 1000000;  // edges per direction
static constexpr int SS = 500000;   // score pairs

// CSR radix-partition geometry
static constexpr int SPAN = 1024;                     // rows per coarse bucket
static constexpr int BKT_G = (NG + SPAN - 1) / SPAN;  // 20
static constexpr int BKT_U = (NU + SPAN - 1) / SPAN;  // 98
static constexpr int PA_BLOCKS = 256;                 // blocks per direction
static constexpr int PA_CHUNK = (EE + PA_BLOCKS - 1) / PA_BLOCKS;  // 3907
static constexpr int TILE = 4096;                     // edges per LDS sort tile
static constexpr int NSC_G = (NG + 1023) / 1024;      // 20 scan blocks
static constexpr int NSC_U = (NU + 1023) / 1024;      // 98 scan blocks

// ---------------- bf16 helpers ----------------
__device__ __forceinline__ float b2f(bf16_t u) {
    union { unsigned int i; float f; } x; x.i = ((unsigned int)u) << 16; return x.f;
}
__device__ __forceinline__ bf16_t f2b(float f) {
    union { float f; unsigned int i; } x; x.f = f;
    unsigned int r = x.i + 0x7FFF + ((x.i >> 16) & 1);  // RNE
    return (bf16_t)(r >> 16);
}

// accumulate 8 bf16 (packed in uint4) * w into acc[8]
__device__ __forceinline__ void accum8(float* acc, uint4 r, float w) {
    unsigned int u[4] = {r.x, r.y, r.z, r.w};
#pragma unroll
    for (int i = 0; i < 4; i++) {
        float lo = __uint_as_float(u[i] << 16);
        float hi = __uint_as_float(u[i] & 0xFFFF0000u);
        acc[2 * i]     = fmaf(w, lo, acc[2 * i]);
        acc[2 * i + 1] = fmaf(w, hi, acc[2 * i + 1]);
    }
}

// ---------------- preprocessing ----------------
__global__ void prep_feats(const float* __restrict__ xgame, const float* __restrict__ emb,
                           const float* __restrict__ xuser,
                           bf16_t* __restrict__ xg, bf16_t* __restrict__ xu,
                           int* __restrict__ gcg, int* __restrict__ gcu) {
    int id = blockIdx.x * 256 + threadIdx.x;
    if (id < BKT_G) gcg[id] = 0;
    if (id < BKT_U) gcu[id] = 0;
    const int ng4 = NG * 32;
    if (id < ng4) {
        int r = id >> 5, c = (id & 31) * 4;
        float4 v = (c < 64) ? *(const float4*)&xgame[(size_t)r * 64 + c]
                            : *(const float4*)&emb[(size_t)r * 64 + (c - 64)];
        ((ushort4*)xg)[id] = make_ushort4(f2b(v.x), f2b(v.y), f2b(v.z), f2b(v.w));
    } else {
        int j = id - ng4;
        if (j >= NU * 32) return;
        float4 v = ((const float4*)xuser)[j];
        ((ushort4*)xu)[j] = make_ushort4(f2b(v.x), f2b(v.y), f2b(v.z), f2b(v.w));
    }
}

struct WtArgs {
    const float* src[12];
    bf16_t* dst[12];
    int K[12];
    int off[13];
};
__global__ void wt_all(WtArgs a, int total) {
    int id = blockIdx.x * 256 + threadIdx.x;
    if (id >= total) return;
    int s = 0;
    while (id >= a.off[s + 1]) ++s;
    int local = id - a.off[s];
    int K = a.K[s];
    int k = local >> 8, n = local & 255;
    a.dst[s][(size_t)n * K + k] = f2b(a.src[s][local]);
}

// ---------------- CSR build: LDS-staged two-level radix partition ----------------
__global__ __launch_bounds__(256) void chisto(const int* __restrict__ dug,
                                              const int* __restrict__ dgu,
                                              int* __restrict__ gcg, int* __restrict__ gcu,
                                              int* __restrict__ rcg, int* __restrict__ rcu) {
    __shared__ int cnt[128];
    int blk = blockIdx.x;
    int gid = blk * 256 + threadIdx.x;
    if (gid < NG) rcg[gid] = 0;
    else if (gid < NG + NU) rcu[gid - NG] = 0;
    int dir = blk >> 8, lb = blk & 255;
    const int* dst = dir ? dgu : dug;
    int* gc = dir ? gcu : gcg;
    int B = dir ? BKT_U : BKT_G;
    int t = threadIdx.x;
    if (t < 128) cnt[t] = 0;
    __syncthreads();
    int beg = lb * PA_CHUNK, fin = min(EE, beg + PA_CHUNK);
    for (int i = beg + t; i < fin; i += 256)
        atomicAdd(&cnt[((unsigned)dst[i]) >> 10], 1);
    __syncthreads();
    if (t < B && cnt[t]) atomicAdd(&gc[t], cnt[t]);
}

__global__ void scan_coarse(const int* __restrict__ gcg, const int* __restrict__ gcu,
                            int* __restrict__ baseg, int* __restrict__ baseu,
                            int* __restrict__ gcurg, int* __restrict__ gcuru,
                            int* __restrict__ rpg, int* __restrict__ rpu) {
    if (blockIdx.x == 0 && threadIdx.x == 0) {
        int run = 0;
        for (int i = 0; i < BKT_G; i++) { baseg[i] = run; gcurg[i] = run; run += gcg[i]; }
        rpg[NG] = EE;
    } else if (blockIdx.x == 1 && threadIdx.x == 0) {
        int run = 0;
        for (int i = 0; i < BKT_U; i++) { baseu[i] = run; gcuru[i] = run; run += gcu[i]; }
        rpu[NU] = EE;
    }
}

__global__ __launch_bounds__(256) void passA(
    const int* __restrict__ sug, const int* __restrict__ dug, const float* __restrict__ wug,
    const int* __restrict__ sgu, const int* __restrict__ dgu, const float* __restrict__ wgu,
    int* __restrict__ gcurg, int* __restrict__ gcuru,
    int2* __restrict__ tmpG, int2* __restrict__ tmpU) {
    __shared__ int cnt[128], sscan[128], gb[128];
    __shared__ unsigned short rankArr[TILE];
    __shared__ unsigned char sbkt[TILE];
    __shared__ int2 staged[TILE];
    int blk = blockIdx.x;
    int dir = blk >> 8, lb = blk & 255;
    const int* src = dir ? sgu : sug;
    const int* dst = dir ? dgu : dug;
    const float* w = dir ? wgu : wug;
    int* gcur = dir ? gcuru : gcurg;
    int2* tmp = dir ? tmpU : tmpG;
    int B = dir ? BKT_U : BKT_G;
    int t = threadIdx.x;
    int beg = lb * PA_CHUNK, fin = min(EE, beg + PA_CHUNK);
    for (int tb = beg; tb < fin; tb += TILE) {
        int n = min(TILE, fin - tb);
        if (t < 128) cnt[t] = 0;
        __syncthreads();
        for (int i = t; i < n; i += 256) {
            int bkt = ((unsigned)dst[tb + i]) >> 10;
            rankArr[i] = (unsigned short)atomicAdd(&cnt[bkt], 1);
        }
        __syncthreads();
        if (t == 0) {
            int run = 0;
            for (int i = 0; i < 128; i++) { sscan[i] = run; run += cnt[i]; }
        }
        __syncthreads();
        for (int i = t; i < n; i += 256) {
            unsigned d = (unsigned)dst[tb + i];
            int bkt = d >> 10;
            int pos = sscan[bkt] + rankArr[i];
            staged[pos] = make_int2(src[tb + i] | ((d & 1023u) << 17), __float_as_int(w[tb + i]));
            sbkt[pos] = (unsigned char)bkt;
        }
        __syncthreads();
        if (t < B && cnt[t]) gb[t] = atomicAdd(&gcur[t], cnt[t]);
        __syncthreads();
        for (int i = t; i < n; i += 256) {
            int bkt = sbkt[i];
            tmp[gb[bkt] + i - sscan[bkt]] = staged[i];
        }
        __syncthreads();
    }
}

// ---- fine phase, parallel: bucket x 8 slices ----
__device__ __forceinline__ void slice_bounds(const int* base, int bkt, int B, int sl,
                                             int& s0, int& s1) {
    int start = base[bkt];
    int end = (bkt == B - 1) ? EE : base[bkt + 1];
    int len = end - start;
    s0 = start + (int)(((long long)len * sl) >> 3);
    s1 = start + (int)(((long long)len * (sl + 1)) >> 3);
}

__global__ __launch_bounds__(256) void passB_hist(
    const int2* __restrict__ tmpG, const int2* __restrict__ tmpU,
    const int* __restrict__ baseg, const int* __restrict__ baseu,
    int* __restrict__ rcg, int* __restrict__ rcu) {
    __shared__ int hist[SPAN];
    int b = blockIdx.x >> 3, sl = blockIdx.x & 7;
    const int2* tmp; const int* base; int* rowcnt; int bkt, B;
    if (b < BKT_G) { tmp = tmpG; base = baseg; rowcnt = rcg; bkt = b; B = BKT_G; }
    else           { tmp = tmpU; base = baseu; rowcnt = rcu; bkt = b - BKT_G; B = BKT_U; }
    int s0, s1;
    slice_bounds(base, bkt, B, sl, s0, s1);
    int t = threadIdx.x;
    for (int i = t; i < SPAN; i += 256) hist[i] = 0;
    __syncthreads();
    for (int i = s0 + t; i < s1; i += 256)
        atomicAdd(&hist[((unsigned)tmp[i].x) >> 17], 1);
    __syncthreads();
    int row0 = bkt * SPAN;
    for (int i = t; i < SPAN; i += 256)
        if (hist[i]) atomicAdd(&rowcnt[row0 + i], hist[i]);
}

__device__ __forceinline__ void scan1_body(const int* cnt, int* rowptr, int* bsum,
                                           int* cur, int n, int lb) {
    __shared__ int sd[256];
    int t = threadIdx.x;
    int base = lb * 1024;
    int v[4]; int s = 0;
#pragma unroll
    for (int i = 0; i < 4; i++) {
        int idx = base + t * 4 + i;
        v[i] = (idx < n) ? cnt[idx] : 0;
        if (idx < n) cur[idx] = 0;
        s += v[i];
    }
    sd[t] = s;
    __syncthreads();
    for (int off = 1; off < 256; off <<= 1) {
        int y = (t >= off) ? sd[t - off] : 0;
        __syncthreads();
        sd[t] += y;
        __syncthreads();
    }
    int run = sd[t] - s;
#pragma unroll
    for (int i = 0; i < 4; i++) {
        int idx = base + t * 4 + i;
        if (idx < n) rowptr[idx] = run;
        run += v[i];
    }
    if (t == 255) bsum[lb] = sd[255];
}

__global__ void scan1b(const int* __restrict__ cg, int* __restrict__ rpg, int* __restrict__ bsg,
                       int* __restrict__ curg,
                       const int* __restrict__ cu, int* __restrict__ rpu, int* __restrict__ bsu,
                       int* __restrict__ curu) {
    int b = blockIdx.x;
    if (b < NSC_G) scan1_body(cg, rpg, bsg, curg, NG, b);
    else           scan1_body(cu, rpu, bsu, curu, NU, b - NSC_G);
}

__global__ void scan2b(int* __restrict__ bsg, int* __restrict__ bsu) {
    if (blockIdx.x != 0) return;
    if (threadIdx.x == 0) {
        int run = 0;
        for (int i = 0; i < NSC_G; i++) { int v = bsg[i]; bsg[i] = run; run += v; }
    } else if (threadIdx.x == 1) {
        int run = 0;
        for (int i = 0; i < NSC_U; i++) { int v = bsu[i]; bsu[i] = run; run += v; }
    }
}

__global__ void scan3b(int* __restrict__ rpg, const int* __restrict__ bsg,
                       int* __restrict__ rpu, const int* __restrict__ bsu) {
    int b = blockIdx.x;
    int t = threadIdx.x;
    if (b < NSC_G) {
        int add = bsg[b];
        int base = b * 1024;
#pragma unroll
        for (int i = 0; i < 4; i++) {
            int idx = base + t * 4 + i;
            if (idx < NG) rpg[idx] += add;
        }
    } else {
        int add = bsu[b - NSC_G];
        int base = (b - NSC_G) * 1024;
#pragma unroll
        for (int i = 0; i < 4; i++) {
            int idx = base + t * 4 + i;
            if (idx < NU) rpu[idx] += add;
        }
    }
}

__global__ __launch_bounds__(256) void passB_scat(
    const int2* __restrict__ tmpG, const int2* __restrict__ tmpU,
    const int* __restrict__ baseg, const int* __restrict__ baseu,
    const int* __restrict__ rpg, const int* __restrict__ rpu,
    int* __restrict__ curg, int* __restrict__ curu,
    int2* __restrict__ eug, int2* __restrict__ egu) {
    int b = blockIdx.x >> 3, sl = blockIdx.x & 7;
    const int2* tmp; const int* base; const int* rowptr; int* cur; int2* eout; int bkt, B;
    if (b < BKT_G) { tmp = tmpG; base = baseg; rowptr = rpg; cur = curg; eout = eug; bkt = b; B = BKT_G; }
    else           { tmp = tmpU; base = baseu; rowptr = rpu; cur = curu; eout = egu; bkt = b - BKT_G; B = BKT_U; }
    int s0, s1;
    slice_bounds(base, bkt, B, sl, s0, s1);
    int row0 = bkt * SPAN;
    for (int i = s0 + threadIdx.x; i < s1; i += 256) {
        int2 e = tmp[i];
        int row = row0 + (int)(((unsigned)e.x) >> 17);
        int pos = rowptr[row] + atomicAdd(&cur[row], 1);
        eout[pos] = make_int2(e.x & 0x1FFFF, e.y);
    }
}

// ---------------- segment sum: wave split into D/8-lane subgroups ----------------
template <int D>  // 128 or 256
__global__ __launch_bounds__(256) void seg_sum16(
    const bf16_t* __restrict__ feat, const int* __restrict__ rowptr,
    const int2* __restrict__ edges, bf16_t* __restrict__ out, int n_rows) {
    constexpr int LPE = D / 8;    // lanes per edge-row (16 B each)
    constexpr int EP = 64 / LPE;  // edges per batch
    constexpr int UN = 4;         // batches in flight
    int wid = (blockIdx.x * 256 + threadIdx.x) >> 6;
    int lane = threadIdx.x & 63;
    if (wid >= n_rows) return;
    int beg = rowptr[wid], end = rowptr[wid + 1];
    const int h = lane / LPE;
    const int cl = lane % LPE;
    const uint4* fb = (const uint4*)feat;
    float acc[8] = {};
    for (int eb = beg; eb < end; eb += UN * EP) {
        int2 ed[UN]; bool v[UN]; uint4 r[UN];
#pragma unroll
        for (int u = 0; u < UN; u++) {
            int e = eb + u * EP + h;
            v[u] = e < end;
            ed[u] = edges[v[u] ? e : beg];
        }
#pragma unroll
        for (int u = 0; u < UN; u++)
            r[u] = fb[(size_t)ed[u].x * (D / 8) + cl];
#pragma unroll
        for (int u = 0; u < UN; u++)
            accum8(acc, r[u], v[u] ? __int_as_float(ed[u].y) : 0.f);
    }
#pragma unroll
    for (int k = 0; k < 8; ++k) {
        acc[k] += __shfl_down(acc[k], 32, 64);
        if (LPE == 16) acc[k] += __shfl_down(acc[k], 16, 64);
    }
    if (lane < LPE) {
        uint4 o;
        o.x = (unsigned)f2b(acc[0]) | ((unsigned)f2b(acc[1]) << 16);
        o.y = (unsigned)f2b(acc[2]) | ((unsigned)f2b(acc[3]) << 16);
        o.z = (unsigned)f2b(acc[4]) | ((unsigned)f2b(acc[5]) << 16);
        o.w = (unsigned)f2b(acc[6]) | ((unsigned)f2b(acc[7]) << 16);
        ((uint4*)(out + (size_t)wid * D))[lane] = o;
    }
}

// ---------------- MFMA GEMM: C(bf16,[M,256]) = A1@W1 (+A2@W2) (+bias) (+C) (relu?) ----
// Operand-swapped MFMA (D = Wt-frag x act-frag) => lane lm holds row wm+i*16+lm,
// regs r = 4 consecutive cols wn+j*16+quad*4+r  => 8-byte vectorized epilogue RMW.
template <bool TWOPASS>
__global__ __launch_bounds__(256) void gemm_mfma(
    const bf16_t* __restrict__ A1, const bf16_t* __restrict__ W1t,
    const bf16_t* __restrict__ A2, const bf16_t* __restrict__ W2t,
    const float* __restrict__ bias, bf16_t* __restrict__ C,
    int M, int K, int addc, int relu) {
    constexpr int LS = 40;
    __shared__ bf16_t As[128 * LS];
    __shared__ bf16_t Bs[128 * LS];
    const int t = threadIdx.x;
    const int lane = t & 63, wave = t >> 6;
    const int wm = (wave >> 1) * 64, wn = (wave & 1) * 64;
    const int rowBase = blockIdx.x * 128;
    const int colBase = blockIdx.y * 128;
    const int lm = lane & 15;
    const int quad = lane >> 4;
    f32x4 acc[4][4] = {};

    const int npass = TWOPASS ? 2 : 1;
    for (int pass = 0; pass < npass; ++pass) {
        const bf16_t* A = pass ? A2 : A1;
        const bf16_t* Wt = pass ? W2t : W1t;
        for (int k0 = 0; k0 < K; k0 += 32) {
#pragma unroll
            for (int i = 0; i < 2; ++i) {
                int li = t + i * 256;
                int r = li >> 2, c = (li & 3) * 8;
                int gm = rowBase + r;
                bf16x8 v = {};
                if (gm < M) v = *(const bf16x8*)&A[(size_t)gm * K + k0 + c];
                *(bf16x8*)&As[r * LS + c] = v;
            }
#pragma unroll
            for (int i = 0; i < 2; ++i) {
                int li = t + i * 256;
                int r = li >> 2, c = (li & 3) * 8;
                bf16x8 v = *(const bf16x8*)&Wt[(size_t)(colBase + r) * K + k0 + c];
                *(bf16x8*)&Bs[r * LS + c] = v;
            }
            __syncthreads();
            bf16x8 af[4], bfr[4];
#pragma unroll
            for (int i = 0; i < 4; ++i)
                af[i] = *(const bf16x8*)&As[(wm + i * 16 + lm) * LS + quad * 8];
#pragma unroll
            for (int j = 0; j < 4; ++j)
                bfr[j] = *(const bf16x8*)&Bs[(wn + j * 16 + lm) * LS + quad * 8];
#pragma unroll
            for (int i = 0; i < 4; ++i)
#pragma unroll
                for (int j = 0; j < 4; ++j)
                    acc[i][j] = __builtin_amdgcn_mfma_f32_16x16x32_bf16(bfr[j], af[i], acc[i][j], 0, 0, 0);
            __syncthreads();
        }
    }

    // epilogue: lane lm -> row; regs -> 4 consecutive cols; 8 B vector RMW
#pragma unroll
    for (int i = 0; i < 4; ++i) {
        int row = rowBase + wm + i * 16 + lm;
        if (row >= M) continue;
#pragma unroll
        for (int j = 0; j < 4; ++j) {
            int col = colBase + wn + j * 16 + quad * 4;
            float v0 = acc[i][j][0], v1 = acc[i][j][1], v2 = acc[i][j][2], v3 = acc[i][j][3];
            if (bias) {
                float4 b4 = *(const float4*)&bias[col];
                v0 += b4.x; v1 += b4.y; v2 += b4.z; v3 += b4.w;
            }
            bf16_t* cp = &C[(size_t)row * HD + col];
            if (addc) {
                ushort4 old = *(const ushort4*)cp;
                v0 += b2f(old.x); v1 += b2f(old.y); v2 += b2f(old.z); v3 += b2f(old.w);
            }
            if (relu) {
                v0 = fmaxf(v0, 0.f); v1 = fmaxf(v1, 0.f);
                v2 = fmaxf(v2, 0.f); v3 = fmaxf(v3, 0.f);
            }
            *(ushort4*)cp = make_ushort4(f2b(v0), f2b(v1), f2b(v2), f2b(v3));
        }
    }
}

// ---------------- decoder: 2 pairs per wave, 16 B loads ----------------
__global__ __launch_bounds__(256) void decode2(
    const bf16_t* __restrict__ u3, const bf16_t* __restrict__ g3,
    const int* __restrict__ row, const int* __restrict__ col,
    float* __restrict__ out, int S) {
    int wid = (blockIdx.x * 256 + threadIdx.x) >> 6;
    int lane = threadIdx.x & 63;
    int p = wid * 2 + (lane >> 5);
    int cl = lane & 31;
    if (p >= S) p = S - 1;  // tail lanes recompute last pair (benign dup store)
    int r = row[p], c = col[p];
    uint4 a = ((const uint4*)(u3 + (size_t)r * 256))[cl];
    uint4 b = ((const uint4*)(g3 + (size_t)c * 256))[cl];
    float s = 0.f;
    unsigned ua[4] = {a.x, a.y, a.z, a.w}, ub[4] = {b.x, b.y, b.z, b.w};
#pragma unroll
    for (int i = 0; i < 4; i++) {
        float alo = __uint_as_float(ua[i] << 16), ahi = __uint_as_float(ua[i] & 0xFFFF0000u);
        float blo = __uint_as_float(ub[i] << 16), bhi = __uint_as_float(ub[i] & 0xFFFF0000u);
        s = fmaf(alo, blo, s);
        s = fmaf(ahi, bhi, s);
    }
#pragma unroll
    for (int d = 16; d > 0; d >>= 1) s += __shfl_down(s, d, 64);
    if (cl == 0) out[p] = s;
}

extern "C" void kernel_launch(void* const* d_in, const int* in_sizes, int n_in,
                              void* d_out, int out_size, void* d_ws, size_t ws_size,
                              hipStream_t stream) {
    const float* x_user  = (const float*)d_in[0];
    const float* x_game  = (const float*)d_in[1];
    const float* emb_game= (const float*)d_in[2];
    const float* ew_ug   = (const float*)d_in[3];
    const float* ew_gu   = (const float*)d_in[4];
    const int* src_ug    = (const int*)d_in[5];
    const int* dst_ug    = (const int*)d_in[6];
    const int* src_gu    = (const int*)d_in[7];
    const int* dst_gu    = (const int*)d_in[8];
    const int* score_row = (const int*)d_in[9];
    const int* score_col = (const int*)d_in[10];
    const float* Wr_ug[3] = {(const float*)d_in[11], (const float*)d_in[17], (const float*)d_in[23]};
    const float* b_ug[3]  = {(const float*)d_in[12], (const float*)d_in[18], (const float*)d_in[24]};
    const float* Wo_g[3]  = {(const float*)d_in[13], (const float*)d_in[19], (const float*)d_in[25]};
    const float* Wr_gu[3] = {(const float*)d_in[14], (const float*)d_in[20], (const float*)d_in[26]};
    const float* b_gu[3]  = {(const float*)d_in[15], (const float*)d_in[21], (const float*)d_in[27]};
    const float* Wo_u[3]  = {(const float*)d_in[16], (const float*)d_in[22], (const float*)d_in[28]};
    float* out = (float*)d_out;
    (void)in_sizes; (void)n_in; (void)out_size;

    constexpr size_t WS_NEEDED = 183500000;
    if (ws_size < WS_NEEDED) return;  // clean fail, no OOB fault

    char* ws = (char*)d_ws;
    size_t off = 0;
    auto alloc = [&](size_t bytes) -> void* {
        void* p = ws + off;
        off += (bytes + 255) & ~(size_t)255;
        return p;
    };
    bf16_t* xg   = (bf16_t*)alloc((size_t)NG * 128 * 2);
    bf16_t* xu   = (bf16_t*)alloc((size_t)NU * 128 * 2);
    bf16_t* uA   = (bf16_t*)alloc((size_t)NU * HD * 2);
    bf16_t* uB   = (bf16_t*)alloc((size_t)NU * HD * 2);
    bf16_t* gA   = (bf16_t*)alloc((size_t)NG * HD * 2);
    bf16_t* gB   = (bf16_t*)alloc((size_t)NG * HD * 2);
    bf16_t* buf  = (bf16_t*)alloc((size_t)NG * HD * 2);
    int2*   e_ug = (int2*)  alloc((size_t)EE * 8);
    int2*   e_gu = (int2*)  alloc((size_t)EE * 8);
    bf16_t* WrugT[3], *WogT[3], *WrguT[3], *WouT[3];
    const int Ks[3] = {128, 256, 256};
    for (int l = 0; l < 3; ++l) {
        WrugT[l] = (bf16_t*)alloc((size_t)Ks[l] * HD * 2);
        WogT[l]  = (bf16_t*)alloc((size_t)Ks[l] * HD * 2);
        WrguT[l] = (bf16_t*)alloc((size_t)Ks[l] * HD * 2);
        WouT[l]  = (bf16_t*)alloc((size_t)Ks[l] * HD * 2);
    }
    int* rowptr_g = (int*)alloc((NG + 1) * 4);
    int* rowptr_u = (int*)alloc((NU + 1) * 4);
    int* rowcnt_g = (int*)alloc(NG * 4);
    int* rowcnt_u = (int*)alloc(NU * 4);
    int* rowcur_g = (int*)alloc(NG * 4);
    int* rowcur_u = (int*)alloc(NU * 4);
    int* gcnt_g   = (int*)alloc(BKT_G * 4);
    int* gcnt_u   = (int*)alloc(BKT_U * 4);
    int* base_g   = (int*)alloc(BKT_G * 4);
    int* base_u   = (int*)alloc(BKT_U * 4);
    int* gcur_g   = (int*)alloc(BKT_G * 4);
    int* gcur_u   = (int*)alloc(BKT_U * 4);
    int* bsum_g   = (int*)alloc(NSC_G * 4);
    int* bsum_u   = (int*)alloc(NSC_U * 4);
    // tmp partition buffers alias uB (dead until layer 2, after passB_scat completes)
    int2* tmp_g = (int2*)uB;
    int2* tmp_u = tmp_g + EE;

    // ---- preprocessing ----
    {
        int n4 = NG * 32 + NU * 32;
        prep_feats<<<(n4 + 255) / 256, 256, 0, stream>>>(x_game, emb_game, x_user, xg, xu,
                                                         gcnt_g, gcnt_u);
        WtArgs wa;
        const float* srcs[12] = {Wr_ug[0], Wo_g[0], Wr_gu[0], Wo_u[0],
                                 Wr_ug[1], Wo_g[1], Wr_gu[1], Wo_u[1],
                                 Wr_ug[2], Wo_g[2], Wr_gu[2], Wo_u[2]};
        bf16_t* dsts[12] = {WrugT[0], WogT[0], WrguT[0], WouT[0],
                            WrugT[1], WogT[1], WrguT[1], WouT[1],
                            WrugT[2], WogT[2], WrguT[2], WouT[2]};
        int total = 0;
        for (int i = 0; i < 12; ++i) {
            wa.src[i] = srcs[i]; wa.dst[i] = dsts[i];
            wa.K[i] = Ks[i / 4]; wa.off[i] = total;
            total += Ks[i / 4] * HD;
        }
        wa.off[12] = total;
        wt_all<<<(total + 255) / 256, 256, 0, stream>>>(wa, total);
    }
    // ---- CSR build ----
    chisto<<<2 * PA_BLOCKS, 256, 0, stream>>>(dst_ug, dst_gu, gcnt_g, gcnt_u,
                                              rowcnt_g, rowcnt_u);
    scan_coarse<<<2, 64, 0, stream>>>(gcnt_g, gcnt_u, base_g, base_u, gcur_g, gcur_u,
                                      rowptr_g, rowptr_u);
    passA<<<2 * PA_BLOCKS, 256, 0, stream>>>(src_ug, dst_ug, ew_ug, src_gu, dst_gu, ew_gu,
                                             gcur_g, gcur_u, tmp_g, tmp_u);
    passB_hist<<<(BKT_G + BKT_U) * 8, 256, 0, stream>>>(tmp_g, tmp_u, base_g, base_u,
                                                        rowcnt_g, rowcnt_u);
    scan1b<<<NSC_G + NSC_U, 256, 0, stream>>>(rowcnt_g, rowptr_g, bsum_g, rowcur_g,
                                              rowcnt_u, rowptr_u, bsum_u, rowcur_u);
    scan2b<<<1, 64, 0, stream>>>(bsum_g, bsum_u);
    scan3b<<<NSC_G + NSC_U, 256, 0, stream>>>(rowptr_g, bsum_g, rowptr_u, bsum_u);
    passB_scat<<<(BKT_G + BKT_U) * 8, 256, 0, stream>>>(tmp_g, tmp_u, base_g, base_u,
                                                        rowptr_g, rowptr_u,
                                                        rowcur_g, rowcur_u, e_ug, e_gu);

    const dim3 GG((NG + 127) / 128, 2), GU((NU + 127) / 128, 2);
    const int SEG_G = (NG + 3) / 4, SEG_U = (NU + 3) / 4;

    // ---- Layer 1 (K=128) ----
    seg_sum16<128><<<SEG_G, 256, 0, stream>>>(xu, rowptr_g, e_ug, buf, NG);
    gemm_mfma<true><<<GG, 256, 0, stream>>>(buf, WrugT[0], xg, WogT[0], b_ug[0], gA, NG, 128, 0, 1);
    gemm_mfma<false><<<GG, 256, 0, stream>>>(xg, WrguT[0], nullptr, nullptr, nullptr, buf, NG, 128, 0, 0);
    seg_sum16<256><<<SEG_U, 256, 0, stream>>>(buf, rowptr_u, e_gu, uA, NU);
    gemm_mfma<false><<<GU, 256, 0, stream>>>(xu, WouT[0], nullptr, nullptr, b_gu[0], uA, NU, 128, 1, 1);

    // ---- Layer 2 (K=256) ----  (uB free now: tmp buffers dead after passB_scat)
    seg_sum16<256><<<SEG_G, 256, 0, stream>>>(uA, rowptr_g, e_ug, buf, NG);
    gemm_mfma<true><<<GG, 256, 0, stream>>>(buf, WrugT[1], gA, WogT[1], b_ug[1], gB, NG, 256, 0, 1);
    gemm_mfma<false><<<GG, 256, 0, stream>>>(gA, WrguT[1], nullptr, nullptr, nullptr, buf, NG, 256, 0, 0);
    seg_sum16<256><<<SEG_U, 256, 0, stream>>>(buf, rowptr_u, e_gu, uB, NU);
    gemm_mfma<false><<<GU, 256, 0, stream>>>(uA, WouT[1], nullptr, nullptr, b_gu[1], uB, NU, 256, 1, 1);

    // ---- Layer 3 (K=256, no relu) ----
    seg_sum16<256><<<SEG_G, 256, 0, stream>>>(uB, rowptr_g, e_ug, buf, NG);
    gemm_mfma<true><<<GG, 256, 0, stream>>>(buf, WrugT[2], gB, WogT[2], b_ug[2], gA, NG, 256, 0, 0);
    gemm_mfma<false><<<GG, 256, 0, stream>>>(gB, WrguT[2], nullptr, nullptr, nullptr, buf, NG, 256, 0, 0);
    seg_sum16<256><<<SEG_U, 256, 0, stream>>>(buf, rowptr_u, e_gu, uA, NU);
    gemm_mfma<false><<<GU, 256, 0, stream>>>(uB, WouT[2], nullptr, nullptr, b_gu[2], uA, NU, 256, 1, 0);

    // ---- decode ----
    decode2<<<((SS + 1) / 2 + 3) / 4, 256, 0, stream>>>(uA, gA, score_row, score_col, out, SS);
}

// Round 9
// 931.736 us; speedup vs baseline: 1.5294x; 1.0556x over previous
//
#include <hip/hip_runtime.h>

typedef unsigned short bf16_t;  // raw bf16 bits
typedef __attribute__((ext_vector_type(8))) short bf16x8;
typedef __attribute__((ext_vector_type(4))) float f32x4;

static constexpr int NU = 100000;   // users
static constexpr int NG = 20000;    // games
static constexpr int HD = 256;      // hidden
static constexpr int EE = 1000000;  // edges per direction
static constexpr int SS = 500000;   // score pairs

// CSR radix-partition geometry: one fine block owns one bucket (fits in LDS)
static constexpr int SH_G = 6,  SPAN_G = 64;    // games: 64 rows/bucket
static constexpr int SH_U = 7,  SPAN_U = 128;   // users: 128 rows/bucket
static constexpr int BKT_G = (NG + SPAN_G - 1) / SPAN_G;  // 313
static constexpr int BKT_U = (NU + SPAN_U - 1) / SPAN_U;  // 782
static constexpr int CAP_G = 4096;  // >= bucket mean 3200 + 15 sigma
static constexpr int CAP_U = 2048;  // >= bucket mean 1280 + 21 sigma
static constexpr int NBMAX = 1024;  // coarse-bucket array size in passA/chisto
static constexpr int PA_BLOCKS = 256;
static constexpr int PA_CHUNK = (EE + PA_BLOCKS - 1) / PA_BLOCKS;  // 3907
static constexpr int TILE = 4096;

// ---------------- bf16 helpers ----------------
__device__ __forceinline__ float b2f(bf16_t u) {
    union { unsigned int i; float f; } x; x.i = ((unsigned int)u) << 16; return x.f;
}
__device__ __forceinline__ bf16_t f2b(float f) {
    union { float f; unsigned int i; } x; x.f = f;
    unsigned int r = x.i + 0x7FFF + ((x.i >> 16) & 1);  // RNE
    return (bf16_t)(r >> 16);
}

// accumulate 8 bf16 (packed in uint4) * w into acc[8]
__device__ __forceinline__ void accum8(float* acc, uint4 r, float w) {
    unsigned int u[4] = {r.x, r.y, r.z, r.w};
#pragma unroll
    for (int i = 0; i < 4; i++) {
        float lo = __uint_as_float(u[i] << 16);
        float hi = __uint_as_float(u[i] & 0xFFFF0000u);
        acc[2 * i]     = fmaf(w, lo, acc[2 * i]);
        acc[2 * i + 1] = fmaf(w, hi, acc[2 * i + 1]);
    }
}

// ---------------- preprocessing ----------------
__global__ void prep_feats(const float* __restrict__ xgame, const float* __restrict__ emb,
                           const float* __restrict__ xuser,
                           bf16_t* __restrict__ xg, bf16_t* __restrict__ xu,
                           int* __restrict__ gcg, int* __restrict__ gcu) {
    int id = blockIdx.x * 256 + threadIdx.x;
    if (id < BKT_G) gcg[id] = 0;
    if (id < BKT_U) gcu[id] = 0;
    const int ng4 = NG * 32;
    if (id < ng4) {
        int r = id >> 5, c = (id & 31) * 4;
        float4 v = (c < 64) ? *(const float4*)&xgame[(size_t)r * 64 + c]
                            : *(const float4*)&emb[(size_t)r * 64 + (c - 64)];
        ((ushort4*)xg)[id] = make_ushort4(f2b(v.x), f2b(v.y), f2b(v.z), f2b(v.w));
    } else {
        int j = id - ng4;
        if (j >= NU * 32) return;
        float4 v = ((const float4*)xuser)[j];
        ((ushort4*)xu)[j] = make_ushort4(f2b(v.x), f2b(v.y), f2b(v.z), f2b(v.w));
    }
}

struct WtArgs {
    const float* src[12];
    bf16_t* dst[12];
    int K[12];
    int off[13];
};
__global__ void wt_all(WtArgs a, int total) {
    int id = blockIdx.x * 256 + threadIdx.x;
    if (id >= total) return;
    int s = 0;
    while (id >= a.off[s + 1]) ++s;
    int local = id - a.off[s];
    int K = a.K[s];
    int k = local >> 8, n = local & 255;
    a.dst[s][(size_t)n * K + k] = f2b(a.src[s][local]);
}

// ---------------- CSR build ----------------
// coarse counts via LDS histogram
__global__ __launch_bounds__(256) void chisto(const int* __restrict__ dug,
                                              const int* __restrict__ dgu,
                                              int* __restrict__ gcg, int* __restrict__ gcu) {
    __shared__ int cnt[NBMAX];
    int blk = blockIdx.x;
    int dir = blk >> 8, lb = blk & 255;
    const int* dst = dir ? dgu : dug;
    int* gc = dir ? gcu : gcg;
    int B = dir ? BKT_U : BKT_G;
    int sh = dir ? SH_U : SH_G;
    int t = threadIdx.x;
    for (int i = t; i < NBMAX; i += 256) cnt[i] = 0;
    __syncthreads();
    int beg = lb * PA_CHUNK, fin = min(EE, beg + PA_CHUNK);
    for (int i = beg + t; i < fin; i += 256)
        atomicAdd(&cnt[((unsigned)dst[i]) >> sh], 1);
    __syncthreads();
    for (int i = t; i < B; i += 256)
        if (cnt[i]) atomicAdd(&gc[i], cnt[i]);
}

// serial exclusive scans over coarse buckets
__global__ void scan_coarse(const int* __restrict__ gcg, const int* __restrict__ gcu,
                            int* __restrict__ baseg, int* __restrict__ baseu,
                            int* __restrict__ gcurg, int* __restrict__ gcuru,
                            int* __restrict__ rpg, int* __restrict__ rpu) {
    if (blockIdx.x == 0 && threadIdx.x == 0) {
        int run = 0;
        for (int i = 0; i < BKT_G; i++) { baseg[i] = run; gcurg[i] = run; run += gcg[i]; }
        rpg[NG] = EE;
    } else if (blockIdx.x == 1 && threadIdx.x == 0) {
        int run = 0;
        for (int i = 0; i < BKT_U; i++) { baseu[i] = run; gcuru[i] = run; run += gcu[i]; }
        rpu[NU] = EE;
    }
}

// LDS tile sort by coarse bucket, then bucket-contiguous burst copy to tmp.
// Entry packs (src | localRow<<17, w); localRow = dst & (SPAN-1).
__global__ __launch_bounds__(256) void passA(
    const int* __restrict__ sug, const int* __restrict__ dug, const float* __restrict__ wug,
    const int* __restrict__ sgu, const int* __restrict__ dgu, const float* __restrict__ wgu,
    int* __restrict__ gcurg, int* __restrict__ gcuru,
    int2* __restrict__ tmpG, int2* __restrict__ tmpU) {
    __shared__ int cnt[NBMAX], sscan[NBMAX], gb[NBMAX], sd[256];
    __shared__ unsigned short rankArr[TILE], sbkt[TILE];
    __shared__ int2 staged[TILE];
    int blk = blockIdx.x;
    int dir = blk >> 8, lb = blk & 255;
    const int* src = dir ? sgu : sug;
    const int* dst = dir ? dgu : dug;
    const float* w = dir ? wgu : wug;
    int* gcur = dir ? gcuru : gcurg;
    int2* tmp = dir ? tmpU : tmpG;
    int B = dir ? BKT_U : BKT_G;
    int sh = dir ? SH_U : SH_G;
    unsigned lmask = dir ? (SPAN_U - 1) : (SPAN_G - 1);
    int t = threadIdx.x;
    int beg = lb * PA_CHUNK, fin = min(EE, beg + PA_CHUNK);
    int n = fin - beg;  // <= TILE
    for (int i = t; i < NBMAX; i += 256) cnt[i] = 0;
    __syncthreads();
    for (int i = t; i < n; i += 256) {
        int bkt = ((unsigned)dst[beg + i]) >> sh;
        rankArr[i] = (unsigned short)atomicAdd(&cnt[bkt], 1);
    }
    __syncthreads();
    {   // parallel exclusive scan of cnt[0..NBMAX) -> sscan
        int v[4]; int s = 0;
#pragma unroll
        for (int j = 0; j < 4; j++) { v[j] = cnt[t * 4 + j]; s += v[j]; }
        sd[t] = s;
        __syncthreads();
        for (int off = 1; off < 256; off <<= 1) {
            int y = (t >= off) ? sd[t - off] : 0;
            __syncthreads();
            sd[t] += y;
            __syncthreads();
        }
        int run = sd[t] - s;
#pragma unroll
        for (int j = 0; j < 4; j++) { sscan[t * 4 + j] = run; run += v[j]; }
    }
    __syncthreads();
    for (int i = t; i < n; i += 256) {
        unsigned d = (unsigned)dst[beg + i];
        int bkt = d >> sh;
        int pos = sscan[bkt] + rankArr[i];
        staged[pos] = make_int2(src[beg + i] | ((d & lmask) << 17), __float_as_int(w[beg + i]));
        sbkt[pos] = (unsigned short)bkt;
    }
    __syncthreads();
    for (int i = t; i < B; i += 256)
        if (cnt[i]) gb[i] = atomicAdd(&gcur[i], cnt[i]);
    __syncthreads();
    for (int i = t; i < n; i += 256) {
        int bkt = sbkt[i];
        tmp[gb[bkt] + i - sscan[bkt]] = staged[i];  // contiguous per-bucket bursts
    }
}

// fine phase: one block owns one bucket; LDS sort; sequential writes; emits rowptr
template <int SPANB, int CAP>
__global__ __launch_bounds__(256) void passB(
    const int2* __restrict__ tmp, const int* __restrict__ base,
    int* __restrict__ rowptr, int2* __restrict__ eout, int B, int ntot) {
    __shared__ int cnt2[SPANB], lexcl[SPANB], cur[SPANB];
    __shared__ int2 staged[CAP];
    constexpr int KMAX = CAP / 256;
    int bkt = blockIdx.x;
    if (bkt >= B) return;
    int start = base[bkt];
    int end = (bkt == B - 1) ? EE : base[bkt + 1];
    int row0 = bkt * SPANB;
    int t = threadIdx.x;
    int count = end - start;
    if (count <= CAP) {  // common path: whole bucket in one LDS chunk
        for (int i = t; i < SPANB; i += 256) cnt2[i] = 0;
        __syncthreads();
        int2 e[KMAX]; int rk[KMAX];
#pragma unroll
        for (int k = 0; k < KMAX; k++) {
            int i = t + k * 256;
            if (i < count) {
                e[k] = tmp[start + i];
                rk[k] = atomicAdd(&cnt2[((unsigned)e[k].x) >> 17], 1);
            }
        }
        __syncthreads();
        if (t == 0) {
            int run = 0;
            for (int r = 0; r < SPANB; r++) { lexcl[r] = run; run += cnt2[r]; }
        }
        __syncthreads();
#pragma unroll
        for (int k = 0; k < KMAX; k++) {
            int i = t + k * 256;
            if (i < count) {
                int r = ((unsigned)e[k].x) >> 17;
                staged[lexcl[r] + rk[k]] = e[k];
            }
        }
        __syncthreads();
        for (int r = t; r < SPANB; r += 256) {
            int row = row0 + r;
            if (row < ntot) rowptr[row] = start + lexcl[r];
        }
        for (int i = t; i < count; i += 256) {
            int2 s = staged[i];
            eout[start + i] = make_int2(s.x & 0x1FFFF, s.y);  // sequential write
        }
    } else {  // overflow fallback: pre-hist + chunked sort with LDS row cursors
        for (int i = t; i < SPANB; i += 256) cnt2[i] = 0;
        __syncthreads();
        for (int i = start + t; i < end; i += 256)
            atomicAdd(&cnt2[((unsigned)tmp[i].x) >> 17], 1);
        __syncthreads();
        if (t == 0) {
            int run = 0;
            for (int r = 0; r < SPANB; r++) { int v = cnt2[r]; cur[r] = run; run += v; }
        }
        __syncthreads();
        for (int r = t; r < SPANB; r += 256) {
            int row = row0 + r;
            if (row < ntot) rowptr[row] = start + cur[r];
        }
        __syncthreads();
        for (int pos = start; pos < end; pos += CAP) {
            int n = min(CAP, end - pos);
            for (int i = t; i < SPANB; i += 256) cnt2[i] = 0;
            __syncthreads();
            int2 e[KMAX]; int rk[KMAX];
#pragma unroll
            for (int k = 0; k < KMAX; k++) {
                int i = t + k * 256;
                if (i < n) {
                    e[k] = tmp[pos + i];
                    rk[k] = atomicAdd(&cnt2[((unsigned)e[k].x) >> 17], 1);
                }
            }
            __syncthreads();
            if (t == 0) {
                int run = 0;
                for (int r = 0; r < SPANB; r++) { lexcl[r] = run; run += cnt2[r]; }
            }
            __syncthreads();
#pragma unroll
            for (int k = 0; k < KMAX; k++) {
                int i = t + k * 256;
                if (i < n) {
                    int r = ((unsigned)e[k].x) >> 17;
                    staged[lexcl[r] + rk[k]] = e[k];
                }
            }
            __syncthreads();
            for (int i = t; i < n; i += 256) {
                int2 s = staged[i];
                int r = ((unsigned)s.x) >> 17;
                int g = start + cur[r] + (i - lexcl[r]);
                eout[g] = make_int2(s.x & 0x1FFFF, s.y);
            }
            __syncthreads();
            for (int r = t; r < SPANB; r += 256) cur[r] += cnt2[r];
            __syncthreads();
        }
    }
}

// ---------------- segment sum: wave split into D/8-lane subgroups ----------------
template <int D>  // 128 or 256
__global__ __launch_bounds__(256) void seg_sum16(
    const bf16_t* __restrict__ feat, const int* __restrict__ rowptr,
    const int2* __restrict__ edges, bf16_t* __restrict__ out, int n_rows) {
    constexpr int LPE = D / 8;    // lanes per edge-row (16 B each)
    constexpr int EP = 64 / LPE;  // edges per batch
    constexpr int UN = 4;         // batches in flight
    int wid = (blockIdx.x * 256 + threadIdx.x) >> 6;
    int lane = threadIdx.x & 63;
    if (wid >= n_rows) return;
    int beg = rowptr[wid], end = rowptr[wid + 1];
    const int h = lane / LPE;
    const int cl = lane % LPE;
    const uint4* fb = (const uint4*)feat;
    float acc[8] = {};
    for (int eb = beg; eb < end; eb += UN * EP) {
        int2 ed[UN]; bool v[UN]; uint4 r[UN];
#pragma unroll
        for (int u = 0; u < UN; u++) {
            int e = eb + u * EP + h;
            v[u] = e < end;
            ed[u] = edges[v[u] ? e : beg];
        }
#pragma unroll
        for (int u = 0; u < UN; u++)
            r[u] = fb[(size_t)ed[u].x * (D / 8) + cl];
#pragma unroll
        for (int u = 0; u < UN; u++)
            accum8(acc, r[u], v[u] ? __int_as_float(ed[u].y) : 0.f);
    }
#pragma unroll
    for (int k = 0; k < 8; ++k) {
        acc[k] += __shfl_down(acc[k], 32, 64);
        if (LPE == 16) acc[k] += __shfl_down(acc[k], 16, 64);
    }
    if (lane < LPE) {
        uint4 o;
        o.x = (unsigned)f2b(acc[0]) | ((unsigned)f2b(acc[1]) << 16);
        o.y = (unsigned)f2b(acc[2]) | ((unsigned)f2b(acc[3]) << 16);
        o.z = (unsigned)f2b(acc[4]) | ((unsigned)f2b(acc[5]) << 16);
        o.w = (unsigned)f2b(acc[6]) | ((unsigned)f2b(acc[7]) << 16);
        ((uint4*)(out + (size_t)wid * D))[lane] = o;
    }
}

// ---------------- MFMA GEMM: C(bf16,[M,256]) = A1@W1 (+A2@W2) (+bias) (+C) (relu?) ----
// Operand-swapped MFMA => lane holds row, regs hold 4 consecutive cols => 8 B epilogue RMW.
template <bool TWOPASS>
__global__ __launch_bounds__(256) void gemm_mfma(
    const bf16_t* __restrict__ A1, const bf16_t* __restrict__ W1t,
    const bf16_t* __restrict__ A2, const bf16_t* __restrict__ W2t,
    const float* __restrict__ bias, bf16_t* __restrict__ C,
    int M, int K, int addc, int relu) {
    constexpr int LS = 40;
    __shared__ bf16_t As[128 * LS];
    __shared__ bf16_t Bs[128 * LS];
    const int t = threadIdx.x;
    const int lane = t & 63, wave = t >> 6;
    const int wm = (wave >> 1) * 64, wn = (wave & 1) * 64;
    const int rowBase = blockIdx.x * 128;
    const int colBase = blockIdx.y * 128;
    const int lm = lane & 15;
    const int quad = lane >> 4;
    f32x4 acc[4][4] = {};

    const int npass = TWOPASS ? 2 : 1;
    for (int pass = 0; pass < npass; ++pass) {
        const bf16_t* A = pass ? A2 : A1;
        const bf16_t* Wt = pass ? W2t : W1t;
        for (int k0 = 0; k0 < K; k0 += 32) {
#pragma unroll
            for (int i = 0; i < 2; ++i) {
                int li = t + i * 256;
                int r = li >> 2, c = (li & 3) * 8;
                int gm = rowBase + r;
                bf16x8 v = {};
                if (gm < M) v = *(const bf16x8*)&A[(size_t)gm * K + k0 + c];
                *(bf16x8*)&As[r * LS + c] = v;
            }
#pragma unroll
            for (int i = 0; i < 2; ++i) {
                int li = t + i * 256;
                int r = li >> 2, c = (li & 3) * 8;
                bf16x8 v = *(const bf16x8*)&Wt[(size_t)(colBase + r) * K + k0 + c];
                *(bf16x8*)&Bs[r * LS + c] = v;
            }
            __syncthreads();
            bf16x8 af[4], bfr[4];
#pragma unroll
            for (int i = 0; i < 4; ++i)
                af[i] = *(const bf16x8*)&As[(wm + i * 16 + lm) * LS + quad * 8];
#pragma unroll
            for (int j = 0; j < 4; ++j)
                bfr[j] = *(const bf16x8*)&Bs[(wn + j * 16 + lm) * LS + quad * 8];
#pragma unroll
            for (int i = 0; i < 4; ++i)
#pragma unroll
                for (int j = 0; j < 4; ++j)
                    acc[i][j] = __builtin_amdgcn_mfma_f32_16x16x32_bf16(bfr[j], af[i], acc[i][j], 0, 0, 0);
            __syncthreads();
        }
    }

#pragma unroll
    for (int i = 0; i < 4; ++i) {
        int row = rowBase + wm + i * 16 + lm;
        if (row >= M) continue;
#pragma unroll
        for (int j = 0; j < 4; ++j) {
            int col = colBase + wn + j * 16 + quad * 4;
            float v0 = acc[i][j][0], v1 = acc[i][j][1], v2 = acc[i][j][2], v3 = acc[i][j][3];
            if (bias) {
                float4 b4 = *(const float4*)&bias[col];
                v0 += b4.x; v1 += b4.y; v2 += b4.z; v3 += b4.w;
            }
            bf16_t* cp = &C[(size_t)row * HD + col];
            if (addc) {
                ushort4 old = *(const ushort4*)cp;
                v0 += b2f(old.x); v1 += b2f(old.y); v2 += b2f(old.z); v3 += b2f(old.w);
            }
            if (relu) {
                v0 = fmaxf(v0, 0.f); v1 = fmaxf(v1, 0.f);
                v2 = fmaxf(v2, 0.f); v3 = fmaxf(v3, 0.f);
            }
            *(ushort4*)cp = make_ushort4(f2b(v0), f2b(v1), f2b(v2), f2b(v3));
        }
    }
}

// ---------------- decoder: 2 pairs per wave, 16 B loads ----------------
__global__ __launch_bounds__(256) void decode2(
    const bf16_t* __restrict__ u3, const bf16_t* __restrict__ g3,
    const int* __restrict__ row, const int* __restrict__ col,
    float* __restrict__ out, int S) {
    int wid = (blockIdx.x * 256 + threadIdx.x) >> 6;
    int lane = threadIdx.x & 63;
    int p = wid * 2 + (lane >> 5);
    int cl = lane & 31;
    if (p >= S) p = S - 1;  // tail lanes recompute last pair (benign dup store)
    int r = row[p], c = col[p];
    uint4 a = ((const uint4*)(u3 + (size_t)r * 256))[cl];
    uint4 b = ((const uint4*)(g3 + (size_t)c * 256))[cl];
    float s = 0.f;
    unsigned ua[4] = {a.x, a.y, a.z, a.w}, ub[4] = {b.x, b.y, b.z, b.w};
#pragma unroll
    for (int i = 0; i < 4; i++) {
        float alo = __uint_as_float(ua[i] << 16), ahi = __uint_as_float(ua[i] & 0xFFFF0000u);
        float blo = __uint_as_float(ub[i] << 16), bhi = __uint_as_float(ub[i] & 0xFFFF0000u);
        s = fmaf(alo, blo, s);
        s = fmaf(ahi, bhi, s);
    }
#pragma unroll
    for (int d = 16; d > 0; d >>= 1) s += __shfl_down(s, d, 64);
    if (cl == 0) out[p] = s;
}

extern "C" void kernel_launch(void* const* d_in, const int* in_sizes, int n_in,
                              void* d_out, int out_size, void* d_ws, size_t ws_size,
                              hipStream_t stream) {
    const float* x_user  = (const float*)d_in[0];
    const float* x_game  = (const float*)d_in[1];
    const float* emb_game= (const float*)d_in[2];
    const float* ew_ug   = (const float*)d_in[3];
    const float* ew_gu   = (const float*)d_in[4];
    const int* src_ug    = (const int*)d_in[5];
    const int* dst_ug    = (const int*)d_in[6];
    const int* src_gu    = (const int*)d_in[7];
    const int* dst_gu    = (const int*)d_in[8];
    const int* score_row = (const int*)d_in[9];
    const int* score_col = (const int*)d_in[10];
    const float* Wr_ug[3] = {(const float*)d_in[11], (const float*)d_in[17], (const float*)d_in[23]};
    const float* b_ug[3]  = {(const float*)d_in[12], (const float*)d_in[18], (const float*)d_in[24]};
    const float* Wo_g[3]  = {(const float*)d_in[13], (const float*)d_in[19], (const float*)d_in[25]};
    const float* Wr_gu[3] = {(const float*)d_in[14], (const float*)d_in[20], (const float*)d_in[26]};
    const float* b_gu[3]  = {(const float*)d_in[15], (const float*)d_in[21], (const float*)d_in[27]};
    const float* Wo_u[3]  = {(const float*)d_in[16], (const float*)d_in[22], (const float*)d_in[28]};
    float* out = (float*)d_out;
    (void)in_sizes; (void)n_in; (void)out_size;

    constexpr size_t WS_NEEDED = 183500000;
    if (ws_size < WS_NEEDED) return;  // clean fail, no OOB fault

    char* ws = (char*)d_ws;
    size_t off = 0;
    auto alloc = [&](size_t bytes) -> void* {
        void* p = ws + off;
        off += (bytes + 255) & ~(size_t)255;
        return p;
    };
    bf16_t* xg   = (bf16_t*)alloc((size_t)NG * 128 * 2);
    bf16_t* xu   = (bf16_t*)alloc((size_t)NU * 128 * 2);
    bf16_t* uA   = (bf16_t*)alloc((size_t)NU * HD * 2);
    bf16_t* uB   = (bf16_t*)alloc((size_t)NU * HD * 2);
    bf16_t* gA   = (bf16_t*)alloc((size_t)NG * HD * 2);
    bf16_t* gB   = (bf16_t*)alloc((size_t)NG * HD * 2);
    bf16_t* buf  = (bf16_t*)alloc((size_t)NG * HD * 2);
    int2*   e_ug = (int2*)  alloc((size_t)EE * 8);
    int2*   e_gu = (int2*)  alloc((size_t)EE * 8);
    bf16_t* WrugT[3], *WogT[3], *WrguT[3], *WouT[3];
    const int Ks[3] = {128, 256, 256};
    for (int l = 0; l < 3; ++l) {
        WrugT[l] = (bf16_t*)alloc((size_t)Ks[l] * HD * 2);
        WogT[l]  = (bf16_t*)alloc((size_t)Ks[l] * HD * 2);
        WrguT[l] = (bf16_t*)alloc((size_t)Ks[l] * HD * 2);
        WouT[l]  = (bf16_t*)alloc((size_t)Ks[l] * HD * 2);
    }
    int* rowptr_g = (int*)alloc((NG + 1) * 4);
    int* rowptr_u = (int*)alloc((NU + 1) * 4);
    int* gcnt_g   = (int*)alloc(BKT_G * 4);
    int* gcnt_u   = (int*)alloc(BKT_U * 4);
    int* base_g   = (int*)alloc(BKT_G * 4);
    int* base_u   = (int*)alloc(BKT_U * 4);
    int* gcur_g   = (int*)alloc(BKT_G * 4);
    int* gcur_u   = (int*)alloc(BKT_U * 4);
    // tmp partition buffers alias uB (dead until layer 2, after passB completes)
    int2* tmp_g = (int2*)uB;
    int2* tmp_u = tmp_g + EE;

    // ---- preprocessing ----
    {
        int n4 = NG * 32 + NU * 32;
        prep_feats<<<(n4 + 255) / 256, 256, 0, stream>>>(x_game, emb_game, x_user, xg, xu,
                                                         gcnt_g, gcnt_u);
        WtArgs wa;
        const float* srcs[12] = {Wr_ug[0], Wo_g[0], Wr_gu[0], Wo_u[0],
                                 Wr_ug[1], Wo_g[1], Wr_gu[1], Wo_u[1],
                                 Wr_ug[2], Wo_g[2], Wr_gu[2], Wo_u[2]};
        bf16_t* dsts[12] = {WrugT[0], WogT[0], WrguT[0], WouT[0],
                            WrugT[1], WogT[1], WrguT[1], WouT[1],
                            WrugT[2], WogT[2], WrguT[2], WouT[2]};
        int total = 0;
        for (int i = 0; i < 12; ++i) {
            wa.src[i] = srcs[i]; wa.dst[i] = dsts[i];
            wa.K[i] = Ks[i / 4]; wa.off[i] = total;
            total += Ks[i / 4] * HD;
        }
        wa.off[12] = total;
        wt_all<<<(total + 255) / 256, 256, 0, stream>>>(wa, total);
    }
    // ---- CSR build ----
    chisto<<<2 * PA_BLOCKS, 256, 0, stream>>>(dst_ug, dst_gu, gcnt_g, gcnt_u);
    scan_coarse<<<2, 64, 0, stream>>>(gcnt_g, gcnt_u, base_g, base_u, gcur_g, gcur_u,
                                      rowptr_g, rowptr_u);
    passA<<<2 * PA_BLOCKS, 256, 0, stream>>>(src_ug, dst_ug, ew_ug, src_gu, dst_gu, ew_gu,
                                             gcur_g, gcur_u, tmp_g, tmp_u);
    passB<SPAN_G, CAP_G><<<BKT_G, 256, 0, stream>>>(tmp_g, base_g, rowptr_g, e_ug, BKT_G, NG);
    passB<SPAN_U, CAP_U><<<BKT_U, 256, 0, stream>>>(tmp_u, base_u, rowptr_u, e_gu, BKT_U, NU);

    const dim3 GG((NG + 127) / 128, 2), GU((NU + 127) / 128, 2);
    const int SEG_G = (NG + 3) / 4, SEG_U = (NU + 3) / 4;

    // ---- Layer 1 (K=128) ----
    seg_sum16<128><<<SEG_G, 256, 0, stream>>>(xu, rowptr_g, e_ug, buf, NG);
    gemm_mfma<true><<<GG, 256, 0, stream>>>(buf, WrugT[0], xg, WogT[0], b_ug[0], gA, NG, 128, 0, 1);
    gemm_mfma<false><<<GG, 256, 0, stream>>>(xg, WrguT[0], nullptr, nullptr, nullptr, buf, NG, 128, 0, 0);
    seg_sum16<256><<<SEG_U, 256, 0, stream>>>(buf, rowptr_u, e_gu, uA, NU);
    gemm_mfma<false><<<GU, 256, 0, stream>>>(xu, WouT[0], nullptr, nullptr, b_gu[0], uA, NU, 128, 1, 1);

    // ---- Layer 2 (K=256) ----  (uB free now: tmp buffers dead after passB)
    seg_sum16<256><<<SEG_G, 256, 0, stream>>>(uA, rowptr_g, e_ug, buf, NG);
    gemm_mfma<true><<<GG, 256, 0, stream>>>(buf, WrugT[1], gA, WogT[1], b_ug[1], gB, NG, 256, 0, 1);
    gemm_mfma<false><<<GG, 256, 0, stream>>>(gA, WrguT[1], nullptr, nullptr, nullptr, buf, NG, 256, 0, 0);
    seg_sum16<256><<<SEG_U, 256, 0, stream>>>(buf, rowptr_u, e_gu, uB, NU);
    gemm_mfma<false><<<GU, 256, 0, stream>>>(uA, WouT[1], nullptr, nullptr, b_gu[1], uB, NU, 256, 1, 1);

    // ---- Layer 3 (K=256, no relu) ----
    seg_sum16<256><<<SEG_G, 256, 0, stream>>>(uB, rowptr_g, e_ug, buf, NG);
    gemm_mfma<true><<<GG, 256, 0, stream>>>(buf, WrugT[2], gB, WogT[2], b_ug[2], gA, NG, 256, 0, 0);
    gemm_mfma<false><<<GG, 256, 0, stream>>>(gB, WrguT[2], nullptr, nullptr, nullptr, buf, NG, 256, 0, 0);
    seg_sum16<256><<<SEG_U, 256, 0, stream>>>(buf, rowptr_u, e_gu, uA, NU);
    gemm_mfma<false><<<GU, 256, 0, stream>>>(uB, WouT[2], nullptr, nullptr, b_gu[2], uA, NU, 256, 1, 0);

    // ---- decode ----
    decode2<<<((SS + 1) / 2 + 3) / 4, 256, 0, stream>>>(uA, gA, score_row, score_col, out, SS);
}